// Round 6
// baseline (822.901 us; speedup 1.0000x reference)
//
#include <hip/hip_runtime.h>
#include <stdint.h>

// ---------------------------------------------------------------------------
// PointNet-style graph autoencoder, MI355X (gfx950).
//
// R12: R11 (best: 766us, edge 203us, VGPR64 no spill) + DEPTH-2 gather
// prefetch in the edge kernel. R11 was VALU 56% / 45%-stall: depth-1 gives
// gq(k+1) only ~300cyc before its pack; random-src gathers are L2-miss/
// L3-hit (~500-900cyc) -> waves stall in lockstep at the pack's vmcnt wait.
// Depth-2 (gq(k+2) issued each iter) gives ~700cyc cover. FIFO-vmcnt rule:
// per iteration issue bfv(k) BEFORE gq(k+2), so MFMA's wait on bfv is
// vmcnt(2) and never drains the youngest gather pair. Live-across-barrier:
// bfv 16 + gq(k+1) 8 + gq(k+2) 8 = 32 regs; (256,3) gives the allocator
// room (~170) -- worst case 3 blocks/CU (37.5% occ) vs stall removal.
// Tripwires: WRITE_SIZE must stay ~62MB, VGPR <= ~80.
// Also: zero_i32 + init_agg fused into one dispatch.
// ---------------------------------------------------------------------------

using bf16x8 = __attribute__((ext_vector_type(8))) short;
using f32x4  = __attribute__((ext_vector_type(4))) float;

#define AB_STRIDE 40      // shorts per staged A row (32 k + 8 pad) -> 16B aligned
#define ABUF      2560    // shorts per A buffer (64 * AB_STRIDE)
#define ZSTRIDE   68      // shorts per Z column (64 rows + 4 pad; pair-balanced)

#define BARRIER_NOVM() asm volatile("s_waitcnt lgkmcnt(0)\n\ts_barrier" ::: "memory")

__device__ __forceinline__ float b2f(uint32_t v16) {          // bf16 bits -> f32
    return __uint_as_float(v16 << 16);
}
__device__ __forceinline__ float b2f_hi(uint32_t w) {         // high bf16 of word
    return __uint_as_float(w & 0xffff0000u);
}
__device__ __forceinline__ uint16_t f2b(float f) {            // f32 -> bf16 (RNE)
    uint32_t u = __float_as_uint(f);
    u += 0x7fffu + ((u >> 16) & 1u);
    return (uint16_t)(u >> 16);
}
#if __has_builtin(__builtin_amdgcn_cvt_pk_bf16_f32)
__device__ __forceinline__ uint32_t pack2bf(float lo, float hi) {
    auto r = __builtin_amdgcn_cvt_pk_bf16_f32(lo, hi);   // RNE
    uint32_t u; __builtin_memcpy(&u, &r, 4); return u;
}
#else
__device__ __forceinline__ uint32_t pack2bf(float lo, float hi) {
    return (uint32_t)f2b(lo) | ((uint32_t)f2b(hi) << 16);
}
#endif
// monotone float<->uint mapping for atomicMax-based segment_max
__device__ __forceinline__ uint32_t encf(float f) {
    uint32_t u = __float_as_uint(f);
    return (u & 0x80000000u) ? ~u : (u | 0x80000000u);
}
__device__ __forceinline__ float decf(uint32_t k) {
    uint32_t u = (k & 0x80000000u) ? (k & 0x7fffffffu) : ~k;
    return __uint_as_float(u);
}

// ---------------------------------------------------------------------------
// Dtype detection. flags[0]=1 if float tensors are fp32 (else bf16),
// flags[1]=1 if edge_index is int64 (else int32).
// ---------------------------------------------------------------------------
__global__ void detect_fmt(const uint32_t* __restrict__ x,
                           const uint32_t* __restrict__ ei,
                           uint32_t* __restrict__ flags) {
    if (threadIdx.x == 0 && blockIdx.x == 0) {
        int plaus = 0;
        for (int i = 0; i < 64; i++) {
            uint32_t v = x[i];
            uint32_t e = (v >> 23) & 0xffu;
            if (v == 0u || (e >= 96u && e <= 150u)) plaus++;
        }
        flags[0] = (plaus >= 48) ? 1u : 0u;
        int zeros = 0;
        for (int i = 0; i < 16; i++)
            if (ei[2 * i + 1] == 0u) zeros++;
        flags[1] = (zeros == 16) ? 1u : 0u;
    }
}

// big float tensor -> canonical bf16 (4 elems/thread)
__global__ __launch_bounds__(256) void convert_big(
        const void* __restrict__ src, uint16_t* __restrict__ dst, int n,
        const uint32_t* __restrict__ flags) {
    bool isf32 = flags[0] != 0u;
    int i = (blockIdx.x * 256 + threadIdx.x) * 4;
    if (i + 3 < n) {
        if (isf32) {
            float4 v = ((const float4*)src)[i >> 2];
            uint2 o = {pack2bf(v.x, v.y), pack2bf(v.z, v.w)};
            ((uint2*)dst)[i >> 2] = o;
        } else {
            ((uint2*)dst)[i >> 2] = ((const uint2*)src)[i >> 2];
        }
    } else {
        for (int j = i; j < n; j++)
            dst[j] = isf32 ? f2b(((const float*)src)[j]) : ((const uint16_t*)src)[j];
    }
}

struct ConvArgs {
    const void* src[13];
    uint32_t dstOff[13];
    uint32_t n[13];
};

// batched small float tensors -> canonical bf16 arena
__global__ __launch_bounds__(256) void convert_small(
        ConvArgs a, uint16_t* __restrict__ dstBase, const uint32_t* __restrict__ flags) {
    bool isf32 = flags[0] != 0u;
    int t = blockIdx.y;
    int i = blockIdx.x * 256 + threadIdx.x;
    if (i >= (int)a.n[t]) return;
    uint16_t* d = dstBase + a.dstOff[t];
    d[i] = isf32 ? f2b(((const float*)a.src[t])[i]) : ((const uint16_t*)a.src[t])[i];
}

// ---------------------------------------------------------------------------
// Counting sort of edges by dst (parallel 3-kernel scan).
// ---------------------------------------------------------------------------
// fused: agg := enc(+0) everywhere; hist := 0 (both uint4-wide)
__global__ __launch_bounds__(256) void init_hist_agg(
        uint32_t* __restrict__ agg, int n4, int* __restrict__ hist, int N) {
    int i = blockIdx.x * 256 + threadIdx.x;
    if (i < n4) {
        uint4 v = {0x80000000u, 0x80000000u, 0x80000000u, 0x80000000u};
        ((uint4*)agg)[i] = v;
    }
    int i4 = i * 4;
    if (i4 + 3 < N) {
        uint4 z = {0, 0, 0, 0};
        ((uint4*)hist)[i] = z;
    } else if (i4 < N) {
        for (int j = i4; j < N; j++) hist[j] = 0;
    }
}

__global__ __launch_bounds__(256) void hist_dst(
        const int* __restrict__ ei_raw, int E, int* __restrict__ hist,
        const uint32_t* __restrict__ flags) {
    bool i64 = flags[1] != 0u;
    int e = blockIdx.x * 256 + threadIdx.x;
    if (e < E) {
        int d = i64 ? ei_raw[2 * (E + e)] : ei_raw[E + e];
        atomicAdd(&hist[d], 1);
    }
}

// per-1024-chunk exclusive scan + chunk totals
__global__ __launch_bounds__(1024) void scan_partial(
        const int* __restrict__ hist, int* __restrict__ cursor,
        int* __restrict__ part, int N) {
    __shared__ int wsum[16];
    int tid = threadIdx.x, lane = tid & 63, wid = tid >> 6;
    int base = blockIdx.x * 1024;
    int v = (base + tid < N) ? hist[base + tid] : 0;
    int x = v;
#pragma unroll
    for (int s = 1; s < 64; s <<= 1) {
        int t = __shfl_up(x, s, 64);
        if (lane >= s) x += t;
    }
    if (lane == 63) wsum[wid] = x;
    __syncthreads();
    if (wid == 0 && lane < 16) {
        int w = wsum[lane];
#pragma unroll
        for (int s = 1; s < 16; s <<= 1) {
            int t = __shfl_up(w, s, 64);
            if (lane >= s) w += t;
        }
        wsum[lane] = w;
    }
    __syncthreads();
    int wbase = (wid > 0) ? wsum[wid - 1] : 0;
    if (base + tid < N) cursor[base + tid] = x - v + wbase;
    if (tid == 0) part[blockIdx.x] = wsum[15];
}

// exclusive scan of chunk totals (B <= 1024)
__global__ __launch_bounds__(1024) void scan_carry(
        const int* __restrict__ part, int* __restrict__ carry, int B) {
    __shared__ int wsum[16];
    int tid = threadIdx.x, lane = tid & 63, wid = tid >> 6;
    int v = (tid < B) ? part[tid] : 0;
    int x = v;
#pragma unroll
    for (int s = 1; s < 64; s <<= 1) {
        int t = __shfl_up(x, s, 64);
        if (lane >= s) x += t;
    }
    if (lane == 63) wsum[wid] = x;
    __syncthreads();
    if (wid == 0 && lane < 16) {
        int w = wsum[lane];
#pragma unroll
        for (int s = 1; s < 16; s <<= 1) {
            int t = __shfl_up(w, s, 64);
            if (lane >= s) w += t;
        }
        wsum[lane] = w;
    }
    __syncthreads();
    int wbase = (wid > 0) ? wsum[wid - 1] : 0;
    if (tid < B) carry[tid] = x - v + wbase;
}

__global__ __launch_bounds__(1024) void scan_add(
        int* __restrict__ cursor, const int* __restrict__ carry, int N) {
    int i = blockIdx.x * 1024 + threadIdx.x;
    if (i < N) cursor[i] += carry[blockIdx.x];
}

__global__ __launch_bounds__(256) void scatter_edges(
        const int* __restrict__ ei_raw, int E, int* __restrict__ cursor,
        int* __restrict__ esrc, int* __restrict__ edst,
        const uint32_t* __restrict__ flags) {
    bool i64 = flags[1] != 0u;
    int e = blockIdx.x * 256 + threadIdx.x;
    if (e < E) {
        int s = i64 ? ei_raw[2 * e] : ei_raw[e];
        int d = i64 ? ei_raw[2 * (E + e)] : ei_raw[E + e];
        int p = atomicAdd(&cursor[d], 1);
        esrc[p] = s;
        edst[p] = d;
    }
}

// ---------------------------------------------------------------------------
// Transpose+chunk-tile the 6 [256x256] B-matrices into WT (32-k chunks):
//   WT[w][ (k>>5)*8192 + n*32 + (k&31) ] = W[k*256 + n]
// ---------------------------------------------------------------------------
__global__ __launch_bounds__(256) void transpose_w(
        const uint16_t* s0, const uint16_t* s1, const uint16_t* s2,
        const uint16_t* s3, const uint16_t* s4, const uint16_t* s5,
        uint16_t* dst) {
    const uint16_t* srcs[6] = {s0, s1, s2, s3, s4, s5};
    const uint16_t* src = srcs[blockIdx.y];
    uint16_t* d = dst + (size_t)blockIdx.y * 65536;
    int k = blockIdx.x;          // grid.x = 256
    int n = threadIdx.x;
    d[(k >> 5) * 8192 + n * 32 + (k & 31)] = src[k * 256 + n];
}

// Q[i][c] = sum_d pos[i][d] * wpos[d][c]   (wpos = wA rows 256..258)
// vectorized: 8 rows/block, 32 threads/row, uint4 (16B) stores.
__global__ __launch_bounds__(256) void pos_proj(
        const uint16_t* pos, const uint16_t* wpos, uint16_t* Q, int N) {
    int t = threadIdx.x;
    int r = t >> 5, c8 = (t & 31) * 8;
    int i = blockIdx.x * 8 + r;
    if (i >= N) return;
    uint4 wv0 = *(const uint4*)(wpos + c8);
    uint4 wv1 = *(const uint4*)(wpos + 256 + c8);
    uint4 wv2 = *(const uint4*)(wpos + 512 + c8);
    float p0 = b2f(pos[i * 3 + 0]);
    float p1 = b2f(pos[i * 3 + 1]);
    float p2 = b2f(pos[i * 3 + 2]);
    uint32_t w0[4] = {wv0.x, wv0.y, wv0.z, wv0.w};
    uint32_t w1[4] = {wv1.x, wv1.y, wv1.z, wv1.w};
    uint32_t w2[4] = {wv2.x, wv2.y, wv2.z, wv2.w};
    uint32_t o[4];
#pragma unroll
    for (int j = 0; j < 4; j++) {
        float lo = p0 * b2f(w0[j] & 0xffffu) + p1 * b2f(w1[j] & 0xffffu) + p2 * b2f(w2[j] & 0xffffu);
        float hi = p0 * b2f_hi(w0[j]) + p1 * b2f_hi(w1[j]) + p2 * b2f_hi(w2[j]);
        o[j] = pack2bf(lo, hi);
    }
    uint4 ov = {o[0], o[1], o[2], o[3]};
    *(uint4*)(Q + (size_t)i * 256 + c8) = ov;
}

// fused: h = bf16(dec(agg)); optionally agg = enc(0) for the next layer
template <int REINIT>
__global__ __launch_bounds__(256) void finalize_init(
        uint32_t* __restrict__ agg, uint16_t* __restrict__ h, int n4) {
    int i = blockIdx.x * 256 + threadIdx.x;
    if (i < n4) {
        uint4 a = ((uint4*)agg)[i];
        uint2 o = {pack2bf(decf(a.x), decf(a.y)), pack2bf(decf(a.z), decf(a.w))};
        ((uint2*)h)[i] = o;
        if (REINIT) {
            uint4 z = {0x80000000u, 0x80000000u, 0x80000000u, 0x80000000u};
            ((uint4*)agg)[i] = z;
        }
    }
}

// ---------------------------------------------------------------------------
// Node GEMM (R11 form; unbounded regs, never spilled). A double-buffered in
// LDS with reg prefetch across the barrier; B fragments direct from L2-hot
// WT, loaded pre-barrier (live across). One lgkm-only barrier per chunk.
// Tile: 64 rows x 256 cols, 256 threads / 4 waves; wave w owns cols [w*64,+64).
// MODE 0: out bf16, +bias +Q (Gs build).  MODE 1: out bf16, +bias, relu.
// MODE 2: out per-flag dtype, +bias (final decoder stage).
// ---------------------------------------------------------------------------
template <int MODE>
__global__ __launch_bounds__(256) void gemm_node(
        const uint16_t* __restrict__ A, const uint16_t* __restrict__ BT,
        const uint16_t* __restrict__ bias, const uint16_t* __restrict__ Qadd,
        void* __restrict__ out, int M, const uint32_t* __restrict__ flags) {
    __shared__ __align__(16) uint16_t Al[2 * 64 * AB_STRIDE];   // 10240 B
    int tid = threadIdx.x;
    int tileM = blockIdx.x;
    int wave = tid >> 6, lane = tid & 63, lrow = lane & 15, quad = lane >> 4;
    int row = tid >> 2, kq = (tid & 3) * 8;
    f32x4 acc[4][4] = {};

    int rg = tileM * 64 + row;
    bool rok = rg < M;
    const uint16_t* abase = A + (size_t)rg * 256 + kq;
    const uint16_t* bfrag = BT + (wave * 64 + lrow) * 32 + quad * 8;
    uint16_t* awr = Al + row * AB_STRIDE + kq;
    const uint16_t* ard = Al + lrow * AB_STRIDE + quad * 8;

    uint4 a0 = {0, 0, 0, 0};
    if (rok) a0 = *(const uint4*)abase;

#pragma unroll
    for (int kc = 0; kc < 256; kc += 32) {
        int buf = (kc >> 5) & 1;
        *(uint4*)(awr + buf * ABUF) = a0;
        // B fragments for this chunk, straight from L2 (live across barrier)
        const uint16_t* bp = bfrag + (kc >> 5) * 8192;
        bf16x8 bfv[4];
#pragma unroll
        for (int c = 0; c < 4; c++) bfv[c] = *(const bf16x8*)(bp + c * 512);
        // prefetch next A chunk (stays in flight across the barrier)
        if (kc < 224 && rok) a0 = *(const uint4*)(abase + kc + 32);
        BARRIER_NOVM();
        const uint16_t* ar = ard + buf * ABUF;
        bf16x8 af[4];
#pragma unroll
        for (int r = 0; r < 4; r++) af[r] = *(const bf16x8*)(ar + r * 16 * AB_STRIDE);
#pragma unroll
        for (int r = 0; r < 4; r++)
#pragma unroll
            for (int c = 0; c < 4; c++)
                acc[r][c] = __builtin_amdgcn_mfma_f32_16x16x32_bf16(af[r], bfv[c], acc[r][c], 0, 0, 0);
    }

    bool of32 = false;
    if (MODE == 2) of32 = flags[0] != 0u;

#pragma unroll
    for (int c = 0; c < 4; c++) {
        int col = wave * 64 + c * 16 + lrow;
        float bv = b2f(bias[col]);
#pragma unroll
        for (int r = 0; r < 4; r++) {
#pragma unroll
            for (int i = 0; i < 4; i++) {
                int rw = tileM * 64 + r * 16 + quad * 4 + i;
                if (rw >= M) continue;
                float v = acc[r][c][i] + bv;
                if (MODE == 0) {
                    v += b2f(Qadd[(size_t)rw * 256 + col]);
                    ((uint16_t*)out)[(size_t)rw * 256 + col] = f2b(v);
                } else if (MODE == 1) {
                    v = fmaxf(v, 0.f);
                    ((uint16_t*)out)[(size_t)rw * 256 + col] = f2b(v);
                } else {
                    if (of32) ((float*)out)[(size_t)rw * 256 + col] = v;
                    else      ((uint16_t*)out)[(size_t)rw * 256 + col] = f2b(v);
                }
            }
        }
    }
}

// ---------------------------------------------------------------------------
// Edge kernel over dst-SORTED edges. Tile = 64 edges x 256 cols, 4 waves.
// R11 pipeline + DEPTH-2 gather prefetch:
//   pack relu(g0-q0) -> Al[buf] (ds_write)       [g0 = gq(k), no vmcnt stall:
//                                                 retired by MFMA(k-1)'s wait]
//   load bfv[4] = B(k) from L2-hot WT            (16 VGPR, live across)
//   rotate g0<-g1; issue g1 = gq(k+2)            (2x8 VGPR, live across;
//                                                 issued AFTER bfv: FIFO!)
//   ONE raw barrier (lgkmcnt(0) only)
//   ds_read af[4]; 16 MFMAs (wait bfv = vmcnt(2) -> newest gathers fly on)
// Epilogue: Z parked col-major in LDS (overlay); run-max scan with ballot
// mask; one coalesced atomicMax per (run, col).
// ---------------------------------------------------------------------------
__global__ __launch_bounds__(256, 3) void edge_gemm_agg(
        const uint16_t* __restrict__ Gs16, const uint16_t* __restrict__ Qb,
        const uint16_t* __restrict__ BT, const uint16_t* __restrict__ bias,
        const int* __restrict__ esrc, const int* __restrict__ edst, int E,
        uint32_t* __restrict__ agg) {
    __shared__ __align__(16) uint16_t SM[256 * ZSTRIDE];     // 34816 B
    uint16_t* Al = SM;                       // dbuf: 2 x 64 x AB_STRIDE = 10240 B
    uint16_t* Zl = SM;                       // overlay: col-major 256 x ZSTRIDE
    __shared__ int sdst[64];
    __shared__ uint64_t smask;
    int tid = threadIdx.x;
    int ebase = blockIdx.x * 64;
    int evalid = (E - ebase < 64) ? (E - ebase) : 64;
    if (tid < 64) sdst[tid] = (tid < evalid) ? edst[ebase + tid] : 0;  // wave 0

    int wave = tid >> 6, lane = tid & 63, lrow = lane & 15, quad = lane >> 4;
    int row = tid >> 2, kq = (tid & 3) * 8;
    int er = (row < evalid) ? row : (evalid - 1);
    int s = esrc[ebase + er];
    int d = edst[ebase + er];
    const uint16_t* gbase = Gs16 + (size_t)s * 256 + kq;
    const uint16_t* qbase = Qb   + (size_t)d * 256 + kq;
    const uint16_t* bfrag = BT + (wave * 64 + lrow) * 32 + quad * 8;
    uint16_t* awr = Al + row * AB_STRIDE + kq;
    const uint16_t* ard = Al + lrow * AB_STRIDE + quad * 8;

    f32x4 acc[4][4] = {};
    uint4 g0 = *(const uint4*)gbase;            // gq(0)
    uint4 q0 = *(const uint4*)qbase;
    uint4 g1 = *(const uint4*)(gbase + 32);     // gq(1)
    uint4 q1 = *(const uint4*)(qbase + 32);

#pragma unroll
    for (int kc = 0; kc < 256; kc += 32) {
        int buf = (kc >> 5) & 1;
        // pack chunk k: relu(g0 - q0) -> bf16 -> Al[buf]
        uint32_t gw[4] = {g0.x, g0.y, g0.z, g0.w};
        uint32_t qw[4] = {q0.x, q0.y, q0.z, q0.w};
        uint32_t mw[4];
#pragma unroll
        for (int j = 0; j < 4; j++) {
            float lo = fmaxf(b2f(gw[j] & 0xffffu) - b2f(qw[j] & 0xffffu), 0.f);
            float hi = fmaxf(b2f_hi(gw[j]) - b2f_hi(qw[j]), 0.f);
            mw[j] = pack2bf(lo, hi);
        }
        uint4 wv = {mw[0], mw[1], mw[2], mw[3]};
        *(uint4*)(awr + buf * ABUF) = wv;
        // B(k) fragments from L2-hot WT -- issued pre-barrier, BEFORE the new
        // gathers (FIFO: MFMA's bfv wait = vmcnt(2) leaves gq(k+2) in flight)
        const uint16_t* bp = bfrag + (kc >> 5) * 8192;
        bf16x8 bfv[4];
#pragma unroll
        for (int c = 0; c < 4; c++) bfv[c] = *(const bf16x8*)(bp + c * 512);
        // rotate prefetch: g0 takes gq(k+1); issue gq(k+2) into g1
        g0 = g1; q0 = q1;
        if (kc < 192) {
            g1 = *(const uint4*)(gbase + kc + 64);
            q1 = *(const uint4*)(qbase + kc + 64);
        }
        BARRIER_NOVM();
        const uint16_t* ar = ard + buf * ABUF;
        bf16x8 af[4];
#pragma unroll
        for (int r = 0; r < 4; r++) af[r] = *(const bf16x8*)(ar + r * 16 * AB_STRIDE);
#pragma unroll
        for (int r = 0; r < 4; r++)
#pragma unroll
            for (int c = 0; c < 4; c++)
                acc[r][c] = __builtin_amdgcn_mfma_f32_16x16x32_bf16(af[r], bfv[c], acc[r][c], 0, 0, 0);
    }
    __syncthreads();          // all waves done reading Al before Z overlays it

    // park z = acc + bias in LDS col-major as bf16 (RNE monotone: commutes w/ max)
    float bv[4];
#pragma unroll
    for (int c = 0; c < 4; c++) bv[c] = b2f(bias[wave * 64 + c * 16 + lrow]);
#pragma unroll
    for (int c = 0; c < 4; c++) {
        int col = wave * 64 + c * 16 + lrow;
#pragma unroll
        for (int r = 0; r < 4; r++) {
            uint2 z4 = {pack2bf(acc[r][c][0] + bv[c], acc[r][c][1] + bv[c]),
                        pack2bf(acc[r][c][2] + bv[c], acc[r][c][3] + bv[c])};
            *(uint2*)&Zl[col * ZSTRIDE + r * 16 + quad * 4] = z4;
        }
    }
    // run-boundary mask (uniform): bit r set where sdst[r] != sdst[r-1]
    if (wave == 0) {
        int d0 = sdst[lane];
        int dp = (lane > 0) ? sdst[lane - 1] : -1;
        uint64_t m = __ballot(d0 != dp);
        if (lane == 0) smask = m;
    }
    __syncthreads();

    // run-max over sorted dst, one coalesced atomic per (run, col)
    uint64_t mask = smask;
    int col = tid;
    const uint16_t* zc = &Zl[col * ZSTRIDE];
    float run = 0.f;
#pragma unroll 4
    for (int gi = 0; gi < 16; gi++) {
        int rbase = gi * 4;
        if (rbase >= evalid) break;
        uint2 z4 = *(const uint2*)&zc[rbase];
        float vv[4] = {b2f(z4.x & 0xffffu), b2f_hi(z4.x),
                       b2f(z4.y & 0xffffu), b2f_hi(z4.y)};
#pragma unroll
        for (int i = 0; i < 4; i++) {
            int r = rbase + i;
            if (r >= evalid) break;
            if (r == 0) {
                run = vv[0];
            } else if ((mask >> r) & 1ull) {
                int dp = sdst[r - 1];
                atomicMax(agg + (size_t)dp * 256 + col, encf(run));
                run = vv[i];
            } else {
                run = fmaxf(run, vv[i]);
            }
        }
    }
    if (evalid > 0)
        atomicMax(agg + (size_t)sdst[evalid - 1] * 256 + col, encf(run));
}

// ---------------------------------------------------------------------------
extern "C" void kernel_launch(void* const* d_in, const int* in_sizes, int n_in,
                              void* d_out, int out_size, void* d_ws, size_t ws_size,
                              hipStream_t stream) {
    const void* x_raw   = d_in[0];
    const void* pos_raw = d_in[1];
    const int*  ei_raw  = (const int*)d_in[2];

    int N = in_sizes[0] / 256;     // 50000
    int E = in_sizes[2] / 2;       // 800000

    // ---- workspace layout (256B-aligned chunks) ----
    char* ws = (char*)d_ws;
    size_t off = 0;
    auto alloc = [&](size_t bytes) { void* p = ws + off; off += (bytes + 255) & ~(size_t)255; return p; };

    uint32_t* flags = (uint32_t*)alloc(256);
    uint16_t* WT    = (uint16_t*)alloc(6 * 65536 * sizeof(uint16_t));          // 768 KB
    const uint32_t POS_OFF = 0;
    const uint32_t W1A_OFF = POS_OFF + (uint32_t)(N * 3);
    const uint32_t W2A_OFF = W1A_OFF + 66304;
    const uint32_t W1B_OFF = W2A_OFF + 66304;
    const uint32_t W2B_OFF = W1B_OFF + 65536;
    const uint32_t WD1_OFF = W2B_OFF + 65536;
    const uint32_t WD2_OFF = WD1_OFF + 65536;
    const uint32_t B1A_OFF = WD2_OFF + 65536;
    const uint32_t B1B_OFF = B1A_OFF + 256;
    const uint32_t B2A_OFF = B1B_OFF + 256;
    const uint32_t B2B_OFF = B2A_OFF + 256;
    const uint32_t BD1_OFF = B2B_OFF + 256;
    const uint32_t BD2_OFF = BD1_OFF + 256;
    const uint32_t ARENA_ELEMS = BD2_OFF + 256;
    uint16_t* arena = (uint16_t*)alloc((size_t)ARENA_ELEMS * 2);
    int*      hist  = (int*)alloc((size_t)N * 4);
    int*      curs  = (int*)alloc((size_t)N * 4);
    int*      part  = (int*)alloc(1024 * 4);
    int*      carry = (int*)alloc(1024 * 4);
    int*      esrc  = (int*)alloc((size_t)E * 4);
    int*      edst  = (int*)alloc((size_t)E * 4);
    uint16_t* Qb    = (uint16_t*)alloc((size_t)N * 256 * 2);                   // 25.6 MB
    uint16_t* Gs    = (uint16_t*)alloc((size_t)N * 256 * 2);                   // 25.6 MB (bf16)
    uint32_t* agg   = (uint32_t*)alloc((size_t)N * 256 * 4);                   // 51.2 MB
    uint16_t* xb    = (uint16_t*)alloc((size_t)N * 256 * 2);                   // 25.6 MB
    uint16_t* h     = xb;               // alias: xb dead after layer-1 node GEMM
    uint16_t* d1    = Gs;               // alias: Gs dead after layer-2 edge pass

    uint16_t* posb = arena + POS_OFF;
    uint16_t* w1a = arena + W1A_OFF, * w2a = arena + W2A_OFF;
    uint16_t* w1b = arena + W1B_OFF, * w2b = arena + W2B_OFF;
    uint16_t* wd1 = arena + WD1_OFF, * wd2 = arena + WD2_OFF;
    uint16_t* b1a = arena + B1A_OFF, * b1b = arena + B1B_OFF;
    uint16_t* b2a = arena + B2A_OFF, * b2b = arena + B2B_OFF;
    uint16_t* bd1 = arena + BD1_OFF, * bd2 = arena + BD2_OFF;

    int n4      = N * 64;
    int nbElem  = (n4 + 255) / 256;
    int nbNode  = (N + 63) / 64;
    int nbEdge  = (E + 63) / 64;
    int nbE256  = (E + 255) / 256;
    int nbPos   = (N + 7) / 8;
    int nbScan  = (N + 1023) / 1024;

    // ---- detection + canonicalization ----
    detect_fmt<<<1, 64, 0, stream>>>((const uint32_t*)x_raw, (const uint32_t*)ei_raw, flags);
    convert_big<<<(N * 256 / 4 + 255) / 256, 256, 0, stream>>>(x_raw, xb, N * 256, flags);

    ConvArgs ca;
    ca.src[0] = pos_raw;  ca.dstOff[0] = POS_OFF; ca.n[0] = (uint32_t)(N * 3);
    ca.src[1] = d_in[3];  ca.dstOff[1] = W1A_OFF; ca.n[1] = 66304;
    ca.src[2] = d_in[7];  ca.dstOff[2] = W2A_OFF; ca.n[2] = 66304;
    ca.src[3] = d_in[5];  ca.dstOff[3] = W1B_OFF; ca.n[3] = 65536;
    ca.src[4] = d_in[9];  ca.dstOff[4] = W2B_OFF; ca.n[4] = 65536;
    ca.src[5] = d_in[11]; ca.dstOff[5] = WD1_OFF; ca.n[5] = 65536;
    ca.src[6] = d_in[13]; ca.dstOff[6] = WD2_OFF; ca.n[6] = 65536;
    ca.src[7] = d_in[4];  ca.dstOff[7] = B1A_OFF; ca.n[7] = 256;
    ca.src[8] = d_in[6];  ca.dstOff[8] = B1B_OFF; ca.n[8] = 256;
    ca.src[9] = d_in[8];  ca.dstOff[9] = B2A_OFF; ca.n[9] = 256;
    ca.src[10] = d_in[10]; ca.dstOff[10] = B2B_OFF; ca.n[10] = 256;
    ca.src[11] = d_in[12]; ca.dstOff[11] = BD1_OFF; ca.n[11] = 256;
    ca.src[12] = d_in[14]; ca.dstOff[12] = BD2_OFF; ca.n[12] = 256;
    {
        uint32_t maxn = (uint32_t)(N * 3);
        dim3 g((maxn + 255) / 256, 13);
        convert_small<<<g, 256, 0, stream>>>(ca, arena, flags);
    }

    // ---- counting sort of edges by dst (once, reused by both layers) ----
    init_hist_agg<<<nbElem, 256, 0, stream>>>(agg, n4, hist, N);
    hist_dst<<<nbE256, 256, 0, stream>>>(ei_raw, E, hist, flags);
    scan_partial<<<nbScan, 1024, 0, stream>>>(hist, curs, part, N);
    scan_carry<<<1, 1024, 0, stream>>>(part, carry, nbScan);
    scan_add<<<nbScan, 1024, 0, stream>>>(curs, carry, N);
    scatter_edges<<<nbE256, 256, 0, stream>>>(ei_raw, E, curs, esrc, edst, flags);

    transpose_w<<<dim3(256, 6), 256, 0, stream>>>(w1a, w1b, w2a, w2b, wd1, wd2, WT);

    // ---- layer 1 ----
    pos_proj<<<nbPos, 256, 0, stream>>>(posb, w1a + 65536, Qb, N);
    gemm_node<0><<<nbNode, 256, 0, stream>>>(xb, WT + 0 * 65536, b1a, Qb, Gs, N, flags);
    edge_gemm_agg<<<nbEdge, 256, 0, stream>>>(Gs, Qb, WT + 1 * 65536, b1b, esrc, edst, E, agg);
    finalize_init<1><<<nbElem, 256, 0, stream>>>(agg, h, n4);

    // ---- layer 2 ----
    pos_proj<<<nbPos, 256, 0, stream>>>(posb, w2a + 65536, Qb, N);
    gemm_node<0><<<nbNode, 256, 0, stream>>>(h, WT + 2 * 65536, b2a, Qb, Gs, N, flags);
    edge_gemm_agg<<<nbEdge, 256, 0, stream>>>(Gs, Qb, WT + 3 * 65536, b2b, esrc, edst, E, agg);
    finalize_init<0><<<nbElem, 256, 0, stream>>>(agg, h, n4);

    // ---- decoder ----
    gemm_node<1><<<nbNode, 256, 0, stream>>>(h, WT + 4 * 65536, bd1, nullptr, d1, N, flags);
    gemm_node<2><<<nbNode, 256, 0, stream>>>(d1, WT + 5 * 65536, bd2, nullptr, d_out, N, flags);
}

// Round 7
// 710.518 us; speedup vs baseline: 1.1582x; 1.1582x over previous
//
#include <hip/hip_runtime.h>
#include <stdint.h>

// ---------------------------------------------------------------------------
// PointNet-style graph autoencoder, MI355X (gfx950).
//
// R13: edge kernel = exact R11 (best measured: 203us, VGPR64, 4 blk/CU;
// R12 proved depth-2 prefetch costs a block of occupancy and loses).
// New: kill the pure-bandwidth passes by fusing into the GEMM A-staging:
//   * convert_big deleted  -- layer-1 gemm_node reads raw x (f32 or bf16 per
//     flag), converting in the staging pack.
//   * finalize_init x2 deleted -- layer-2 gemm_node + decoder stage-1 read
//     agg (encoded u32) directly, decode in the staging pack; the layer-2
//     variant writes enc(0) back after its K-loop (each row is read by
//     exactly one block; per-thread 32B spans are disjoint -> race-free).
// gemm_node mirrors the edge pipeline exactly incl. __launch_bounds__(256,3)
// (live-across = bfv16 + A-prefetch8 <= edge's 24 -> 4 blocks/CU).
// Saves ~340MB of HBM round-trips and 3 dispatches.
// ---------------------------------------------------------------------------

using bf16x8 = __attribute__((ext_vector_type(8))) short;
using f32x4  = __attribute__((ext_vector_type(4))) float;

#define AB_STRIDE 40      // shorts per staged A row (32 k + 8 pad) -> 16B aligned
#define ABUF      2560    // shorts per A buffer (64 * AB_STRIDE)
#define ZSTRIDE   68      // shorts per Z column (64 rows + 4 pad)

#define BARRIER_NOVM() asm volatile("s_waitcnt lgkmcnt(0)\n\ts_barrier" ::: "memory")

__device__ __forceinline__ float b2f(uint32_t v16) {          // bf16 bits -> f32
    return __uint_as_float(v16 << 16);
}
__device__ __forceinline__ float b2f_hi(uint32_t w) {         // high bf16 of word
    return __uint_as_float(w & 0xffff0000u);
}
__device__ __forceinline__ uint16_t f2b(float f) {            // f32 -> bf16 (RNE)
    uint32_t u = __float_as_uint(f);
    u += 0x7fffu + ((u >> 16) & 1u);
    return (uint16_t)(u >> 16);
}
#if __has_builtin(__builtin_amdgcn_cvt_pk_bf16_f32)
__device__ __forceinline__ uint32_t pack2bf(float lo, float hi) {
    auto r = __builtin_amdgcn_cvt_pk_bf16_f32(lo, hi);   // RNE
    uint32_t u; __builtin_memcpy(&u, &r, 4); return u;
}
#else
__device__ __forceinline__ uint32_t pack2bf(float lo, float hi) {
    return (uint32_t)f2b(lo) | ((uint32_t)f2b(hi) << 16);
}
#endif
// monotone float<->uint mapping for atomicMax-based segment_max
__device__ __forceinline__ uint32_t encf(float f) {
    uint32_t u = __float_as_uint(f);
    return (u & 0x80000000u) ? ~u : (u | 0x80000000u);
}
__device__ __forceinline__ float decf(uint32_t k) {
    uint32_t u = (k & 0x80000000u) ? (k & 0x7fffffffu) : ~k;
    return __uint_as_float(u);
}

// ---------------------------------------------------------------------------
// Dtype detection. flags[0]=1 if float tensors are fp32 (else bf16),
// flags[1]=1 if edge_index is int64 (else int32).
// ---------------------------------------------------------------------------
__global__ void detect_fmt(const uint32_t* __restrict__ x,
                           const uint32_t* __restrict__ ei,
                           uint32_t* __restrict__ flags) {
    if (threadIdx.x == 0 && blockIdx.x == 0) {
        int plaus = 0;
        for (int i = 0; i < 64; i++) {
            uint32_t v = x[i];
            uint32_t e = (v >> 23) & 0xffu;
            if (v == 0u || (e >= 96u && e <= 150u)) plaus++;
        }
        flags[0] = (plaus >= 48) ? 1u : 0u;
        int zeros = 0;
        for (int i = 0; i < 16; i++)
            if (ei[2 * i + 1] == 0u) zeros++;
        flags[1] = (zeros == 16) ? 1u : 0u;
    }
}

struct ConvArgs {
    const void* src[13];
    uint32_t dstOff[13];
    uint32_t n[13];
};

// batched small float tensors -> canonical bf16 arena
__global__ __launch_bounds__(256) void convert_small(
        ConvArgs a, uint16_t* __restrict__ dstBase, const uint32_t* __restrict__ flags) {
    bool isf32 = flags[0] != 0u;
    int t = blockIdx.y;
    int i = blockIdx.x * 256 + threadIdx.x;
    if (i >= (int)a.n[t]) return;
    uint16_t* d = dstBase + a.dstOff[t];
    d[i] = isf32 ? f2b(((const float*)a.src[t])[i]) : ((const uint16_t*)a.src[t])[i];
}

// ---------------------------------------------------------------------------
// Counting sort of edges by dst (parallel 3-kernel scan).
// ---------------------------------------------------------------------------
// fused: agg := enc(+0) everywhere; hist := 0 (both uint4-wide)
__global__ __launch_bounds__(256) void init_hist_agg(
        uint32_t* __restrict__ agg, int n4, int* __restrict__ hist, int N) {
    int i = blockIdx.x * 256 + threadIdx.x;
    if (i < n4) {
        uint4 v = {0x80000000u, 0x80000000u, 0x80000000u, 0x80000000u};
        ((uint4*)agg)[i] = v;
    }
    int i4 = i * 4;
    if (i4 + 3 < N) {
        uint4 z = {0, 0, 0, 0};
        ((uint4*)hist)[i] = z;
    } else if (i4 < N) {
        for (int j = i4; j < N; j++) hist[j] = 0;
    }
}

__global__ __launch_bounds__(256) void hist_dst(
        const int* __restrict__ ei_raw, int E, int* __restrict__ hist,
        const uint32_t* __restrict__ flags) {
    bool i64 = flags[1] != 0u;
    int e = blockIdx.x * 256 + threadIdx.x;
    if (e < E) {
        int d = i64 ? ei_raw[2 * (E + e)] : ei_raw[E + e];
        atomicAdd(&hist[d], 1);
    }
}

// per-1024-chunk exclusive scan + chunk totals
__global__ __launch_bounds__(1024) void scan_partial(
        const int* __restrict__ hist, int* __restrict__ cursor,
        int* __restrict__ part, int N) {
    __shared__ int wsum[16];
    int tid = threadIdx.x, lane = tid & 63, wid = tid >> 6;
    int base = blockIdx.x * 1024;
    int v = (base + tid < N) ? hist[base + tid] : 0;
    int x = v;
#pragma unroll
    for (int s = 1; s < 64; s <<= 1) {
        int t = __shfl_up(x, s, 64);
        if (lane >= s) x += t;
    }
    if (lane == 63) wsum[wid] = x;
    __syncthreads();
    if (wid == 0 && lane < 16) {
        int w = wsum[lane];
#pragma unroll
        for (int s = 1; s < 16; s <<= 1) {
            int t = __shfl_up(w, s, 64);
            if (lane >= s) w += t;
        }
        wsum[lane] = w;
    }
    __syncthreads();
    int wbase = (wid > 0) ? wsum[wid - 1] : 0;
    if (base + tid < N) cursor[base + tid] = x - v + wbase;
    if (tid == 0) part[blockIdx.x] = wsum[15];
}

// exclusive scan of chunk totals (B <= 1024)
__global__ __launch_bounds__(1024) void scan_carry(
        const int* __restrict__ part, int* __restrict__ carry, int B) {
    __shared__ int wsum[16];
    int tid = threadIdx.x, lane = tid & 63, wid = tid >> 6;
    int v = (tid < B) ? part[tid] : 0;
    int x = v;
#pragma unroll
    for (int s = 1; s < 64; s <<= 1) {
        int t = __shfl_up(x, s, 64);
        if (lane >= s) x += t;
    }
    if (lane == 63) wsum[wid] = x;
    __syncthreads();
    if (wid == 0 && lane < 16) {
        int w = wsum[lane];
#pragma unroll
        for (int s = 1; s < 16; s <<= 1) {
            int t = __shfl_up(w, s, 64);
            if (lane >= s) w += t;
        }
        wsum[lane] = w;
    }
    __syncthreads();
    int wbase = (wid > 0) ? wsum[wid - 1] : 0;
    if (tid < B) carry[tid] = x - v + wbase;
}

__global__ __launch_bounds__(1024) void scan_add(
        int* __restrict__ cursor, const int* __restrict__ carry, int N) {
    int i = blockIdx.x * 1024 + threadIdx.x;
    if (i < N) cursor[i] += carry[blockIdx.x];
}

__global__ __launch_bounds__(256) void scatter_edges(
        const int* __restrict__ ei_raw, int E, int* __restrict__ cursor,
        int* __restrict__ esrc, int* __restrict__ edst,
        const uint32_t* __restrict__ flags) {
    bool i64 = flags[1] != 0u;
    int e = blockIdx.x * 256 + threadIdx.x;
    if (e < E) {
        int s = i64 ? ei_raw[2 * e] : ei_raw[e];
        int d = i64 ? ei_raw[2 * (E + e)] : ei_raw[E + e];
        int p = atomicAdd(&cursor[d], 1);
        esrc[p] = s;
        edst[p] = d;
    }
}

// ---------------------------------------------------------------------------
// Transpose+chunk-tile the 6 [256x256] B-matrices into WT (32-k chunks):
//   WT[w][ (k>>5)*8192 + n*32 + (k&31) ] = W[k*256 + n]
// ---------------------------------------------------------------------------
__global__ __launch_bounds__(256) void transpose_w(
        const uint16_t* s0, const uint16_t* s1, const uint16_t* s2,
        const uint16_t* s3, const uint16_t* s4, const uint16_t* s5,
        uint16_t* dst) {
    const uint16_t* srcs[6] = {s0, s1, s2, s3, s4, s5};
    const uint16_t* src = srcs[blockIdx.y];
    uint16_t* d = dst + (size_t)blockIdx.y * 65536;
    int k = blockIdx.x;          // grid.x = 256
    int n = threadIdx.x;
    d[(k >> 5) * 8192 + n * 32 + (k & 31)] = src[k * 256 + n];
}

// Q[i][c] = sum_d pos[i][d] * wpos[d][c]   (wpos = wA rows 256..258)
// vectorized: 8 rows/block, 32 threads/row, uint4 (16B) stores.
__global__ __launch_bounds__(256) void pos_proj(
        const uint16_t* pos, const uint16_t* wpos, uint16_t* Q, int N) {
    int t = threadIdx.x;
    int r = t >> 5, c8 = (t & 31) * 8;
    int i = blockIdx.x * 8 + r;
    if (i >= N) return;
    uint4 wv0 = *(const uint4*)(wpos + c8);
    uint4 wv1 = *(const uint4*)(wpos + 256 + c8);
    uint4 wv2 = *(const uint4*)(wpos + 512 + c8);
    float p0 = b2f(pos[i * 3 + 0]);
    float p1 = b2f(pos[i * 3 + 1]);
    float p2 = b2f(pos[i * 3 + 2]);
    uint32_t w0[4] = {wv0.x, wv0.y, wv0.z, wv0.w};
    uint32_t w1[4] = {wv1.x, wv1.y, wv1.z, wv1.w};
    uint32_t w2[4] = {wv2.x, wv2.y, wv2.z, wv2.w};
    uint32_t o[4];
#pragma unroll
    for (int j = 0; j < 4; j++) {
        float lo = p0 * b2f(w0[j] & 0xffffu) + p1 * b2f(w1[j] & 0xffffu) + p2 * b2f(w2[j] & 0xffffu);
        float hi = p0 * b2f_hi(w0[j]) + p1 * b2f_hi(w1[j]) + p2 * b2f_hi(w2[j]);
        o[j] = pack2bf(lo, hi);
    }
    uint4 ov = {o[0], o[1], o[2], o[3]};
    *(uint4*)(Q + (size_t)i * 256 + c8) = ov;
}

// ---------------------------------------------------------------------------
// Node GEMM, R11 edge pipeline mirrored ((256,3); A dbuf in LDS with reg
// prefetch across one lgkm-only barrier; B fragments from L2-hot WT loaded
// pre-barrier, live across). A-staging converts per AMODE:
//   AMODE 0: A is bf16 rows (pass-through)
//   AMODE 1: A is agg-encoded u32 rows -> decf -> bf16; REINIT=1 writes
//            enc(0) back after the K-loop (row owned by this block;
//            per-thread 32B spans disjoint -> race-free)
//   AMODE 2: A is raw x: f32 (convert) or bf16 (pass-through) per flags[0]
// OUTMODE 0: bf16 +bias +Q.  1: bf16 +bias relu.  2: flag-dtype +bias.
// ---------------------------------------------------------------------------
template <int AMODE, int OUTMODE, int REINIT>
__global__ __launch_bounds__(256, 3) void gemm_node(
        const void* __restrict__ Araw, const uint16_t* __restrict__ BT,
        const uint16_t* __restrict__ bias, const uint16_t* __restrict__ Qadd,
        void* __restrict__ out, int M, const uint32_t* __restrict__ flags,
        uint32_t* __restrict__ aggwb) {
    __shared__ __align__(16) uint16_t Al[2 * 64 * AB_STRIDE];   // 10240 B
    int tid = threadIdx.x;
    int tileM = blockIdx.x;
    int wave = tid >> 6, lane = tid & 63, lrow = lane & 15, quad = lane >> 4;
    int row = tid >> 2, kq = (tid & 3) * 8;
    f32x4 acc[4][4] = {};

    int rg = tileM * 64 + row;
    bool rok = rg < M;
    int rgc = rok ? rg : (M - 1);            // clamp: keep vm counts uniform
    bool isf32 = false;
    if (AMODE == 2 || OUTMODE == 2) isf32 = flags[0] != 0u;

    const uint16_t* a16 = (const uint16_t*)Araw + (size_t)rgc * 256 + kq;
    const uint32_t* a32 = (const uint32_t*)Araw + (size_t)rgc * 256 + kq;
    const uint16_t* bfrag = BT + (wave * 64 + lrow) * 32 + quad * 8;
    uint16_t* awr = Al + row * AB_STRIDE + kq;
    const uint16_t* ard = Al + lrow * AB_STRIDE + quad * 8;

    // prefetch A chunk 0 (p0 [, p1] live across the barrier)
    uint4 p0 = {0, 0, 0, 0}, p1 = {0, 0, 0, 0};
    if (AMODE == 0) {
        p0 = *(const uint4*)a16;
    } else if (AMODE == 1) {
        p0 = *(const uint4*)a32; p1 = *(const uint4*)(a32 + 4);
    } else {
        if (isf32) { p0 = *(const uint4*)a32; p1 = *(const uint4*)(a32 + 4); }
        else       { p0 = *(const uint4*)a16; }
    }

#pragma unroll
    for (int kc = 0; kc < 256; kc += 32) {
        int buf = (kc >> 5) & 1;
        // stage A chunk -> Al[buf], converting per AMODE
        uint4 wv;
        if (AMODE == 0 || (AMODE == 2 && !isf32)) {
            wv = p0;
        } else if (AMODE == 1) {
            uint32_t a[8] = {p0.x, p0.y, p0.z, p0.w, p1.x, p1.y, p1.z, p1.w};
            wv.x = pack2bf(decf(a[0]), decf(a[1]));
            wv.y = pack2bf(decf(a[2]), decf(a[3]));
            wv.z = pack2bf(decf(a[4]), decf(a[5]));
            wv.w = pack2bf(decf(a[6]), decf(a[7]));
        } else {   // raw f32
            wv.x = pack2bf(__uint_as_float(p0.x), __uint_as_float(p0.y));
            wv.y = pack2bf(__uint_as_float(p0.z), __uint_as_float(p0.w));
            wv.z = pack2bf(__uint_as_float(p1.x), __uint_as_float(p1.y));
            wv.w = pack2bf(__uint_as_float(p1.z), __uint_as_float(p1.w));
        }
        *(uint4*)(awr + buf * ABUF) = wv;
        // B fragments for this chunk, straight from L2 (live across barrier)
        const uint16_t* bp = bfrag + (kc >> 5) * 8192;
        bf16x8 bfv[4];
#pragma unroll
        for (int c = 0; c < 4; c++) bfv[c] = *(const bf16x8*)(bp + c * 512);
        // prefetch next A chunk (stays in flight across the barrier)
        if (kc < 224) {
            if (AMODE == 0) {
                p0 = *(const uint4*)(a16 + kc + 32);
            } else if (AMODE == 1) {
                p0 = *(const uint4*)(a32 + kc + 32);
                p1 = *(const uint4*)(a32 + kc + 36);
            } else {
                if (isf32) { p0 = *(const uint4*)(a32 + kc + 32);
                             p1 = *(const uint4*)(a32 + kc + 36); }
                else       { p0 = *(const uint4*)(a16 + kc + 32); }
            }
        }
        BARRIER_NOVM();
        const uint16_t* ar = ard + buf * ABUF;
        bf16x8 af[4];
#pragma unroll
        for (int r = 0; r < 4; r++) af[r] = *(const bf16x8*)(ar + r * 16 * AB_STRIDE);
#pragma unroll
        for (int r = 0; r < 4; r++)
#pragma unroll
            for (int c = 0; c < 4; c++)
                acc[r][c] = __builtin_amdgcn_mfma_f32_16x16x32_bf16(af[r], bfv[c], acc[r][c], 0, 0, 0);
    }

    // agg re-init writeback (layer-2 Gs build): this block owns these rows
    if (AMODE == 1 && REINIT && rok) {
        uint32_t* wb = aggwb + (size_t)rg * 256 + kq;
        uint4 z = {0x80000000u, 0x80000000u, 0x80000000u, 0x80000000u};
#pragma unroll
        for (int kc = 0; kc < 256; kc += 32) {
            *(uint4*)(wb + kc) = z;
            *(uint4*)(wb + kc + 4) = z;
        }
    }

#pragma unroll
    for (int c = 0; c < 4; c++) {
        int col = wave * 64 + c * 16 + lrow;
        float bv = b2f(bias[col]);
#pragma unroll
        for (int r = 0; r < 4; r++) {
#pragma unroll
            for (int i = 0; i < 4; i++) {
                int rw = tileM * 64 + r * 16 + quad * 4 + i;
                if (rw >= M) continue;
                float v = acc[r][c][i] + bv;
                if (OUTMODE == 0) {
                    v += b2f(Qadd[(size_t)rw * 256 + col]);
                    ((uint16_t*)out)[(size_t)rw * 256 + col] = f2b(v);
                } else if (OUTMODE == 1) {
                    v = fmaxf(v, 0.f);
                    ((uint16_t*)out)[(size_t)rw * 256 + col] = f2b(v);
                } else {
                    if (isf32) ((float*)out)[(size_t)rw * 256 + col] = v;
                    else       ((uint16_t*)out)[(size_t)rw * 256 + col] = f2b(v);
                }
            }
        }
    }
}

// ---------------------------------------------------------------------------
// Edge kernel over dst-SORTED edges. EXACT R11 (best: 203us, VGPR64,
// 4 blk/CU). Tile = 64 edges x 256 cols, 4 waves. Per chunk:
//   pack relu(g-q) -> Al[buf]; load bfv[4] (live across); prefetch gq(k+1)
//   (live across); ONE lgkm-only barrier; ds_read af; 16 MFMAs.
// Epilogue: Z parked col-major in LDS (overlay); run-max scan with ballot
// mask; one coalesced atomicMax per (run, col).
// ---------------------------------------------------------------------------
__global__ __launch_bounds__(256, 3) void edge_gemm_agg(
        const uint16_t* __restrict__ Gs16, const uint16_t* __restrict__ Qb,
        const uint16_t* __restrict__ BT, const uint16_t* __restrict__ bias,
        const int* __restrict__ esrc, const int* __restrict__ edst, int E,
        uint32_t* __restrict__ agg) {
    __shared__ __align__(16) uint16_t SM[256 * ZSTRIDE];     // 34816 B
    uint16_t* Al = SM;                       // dbuf: 2 x 64 x AB_STRIDE = 10240 B
    uint16_t* Zl = SM;                       // overlay: col-major 256 x ZSTRIDE
    __shared__ int sdst[64];
    __shared__ uint64_t smask;
    int tid = threadIdx.x;
    int ebase = blockIdx.x * 64;
    int evalid = (E - ebase < 64) ? (E - ebase) : 64;
    if (tid < 64) sdst[tid] = (tid < evalid) ? edst[ebase + tid] : 0;  // wave 0

    int wave = tid >> 6, lane = tid & 63, lrow = lane & 15, quad = lane >> 4;
    int row = tid >> 2, kq = (tid & 3) * 8;
    int er = (row < evalid) ? row : (evalid - 1);
    int s = esrc[ebase + er];
    int d = edst[ebase + er];
    const uint16_t* gbase = Gs16 + (size_t)s * 256 + kq;
    const uint16_t* qbase = Qb   + (size_t)d * 256 + kq;
    const uint16_t* bfrag = BT + (wave * 64 + lrow) * 32 + quad * 8;
    uint16_t* awr = Al + row * AB_STRIDE + kq;
    const uint16_t* ard = Al + lrow * AB_STRIDE + quad * 8;

    f32x4 acc[4][4] = {};
    uint4 g = *(const uint4*)gbase;          // gathers for chunk 0
    uint4 q = *(const uint4*)qbase;

#pragma unroll
    for (int kc = 0; kc < 256; kc += 32) {
        int buf = (kc >> 5) & 1;
        // pack current chunk: relu(g - q) -> bf16 -> Al[buf]
        uint32_t gw[4] = {g.x, g.y, g.z, g.w};
        uint32_t qw[4] = {q.x, q.y, q.z, q.w};
        uint32_t mw[4];
#pragma unroll
        for (int j = 0; j < 4; j++) {
            float lo = fmaxf(b2f(gw[j] & 0xffffu) - b2f(qw[j] & 0xffffu), 0.f);
            float hi = fmaxf(b2f_hi(gw[j]) - b2f_hi(qw[j]), 0.f);
            mw[j] = pack2bf(lo, hi);
        }
        uint4 wv = {mw[0], mw[1], mw[2], mw[3]};
        *(uint4*)(awr + buf * ABUF) = wv;
        // B(k) fragments from L2-hot WT -- issued pre-barrier, live across
        const uint16_t* bp = bfrag + (kc >> 5) * 8192;
        bf16x8 bfv[4];
#pragma unroll
        for (int c = 0; c < 4; c++) bfv[c] = *(const bf16x8*)(bp + c * 512);
        // prefetch gathers(k+1): fly across the barrier, land during MFMAs
        if (kc < 224) {
            g = *(const uint4*)(gbase + kc + 32);
            q = *(const uint4*)(qbase + kc + 32);
        }
        BARRIER_NOVM();
        const uint16_t* ar = ard + buf * ABUF;
        bf16x8 af[4];
#pragma unroll
        for (int r = 0; r < 4; r++) af[r] = *(const bf16x8*)(ar + r * 16 * AB_STRIDE);
#pragma unroll
        for (int r = 0; r < 4; r++)
#pragma unroll
            for (int c = 0; c < 4; c++)
                acc[r][c] = __builtin_amdgcn_mfma_f32_16x16x32_bf16(af[r], bfv[c], acc[r][c], 0, 0, 0);
    }
    __syncthreads();          // all waves done reading Al before Z overlays it

    // park z = acc + bias in LDS col-major as bf16 (RNE monotone: commutes w/ max)
    float bv[4];
#pragma unroll
    for (int c = 0; c < 4; c++) bv[c] = b2f(bias[wave * 64 + c * 16 + lrow]);
#pragma unroll
    for (int c = 0; c < 4; c++) {
        int col = wave * 64 + c * 16 + lrow;
#pragma unroll
        for (int r = 0; r < 4; r++) {
            uint2 z4 = {pack2bf(acc[r][c][0] + bv[c], acc[r][c][1] + bv[c]),
                        pack2bf(acc[r][c][2] + bv[c], acc[r][c][3] + bv[c])};
            *(uint2*)&Zl[col * ZSTRIDE + r * 16 + quad * 4] = z4;
        }
    }
    // run-boundary mask (uniform): bit r set where sdst[r] != sdst[r-1]
    if (wave == 0) {
        int d0 = sdst[lane];
        int dp = (lane > 0) ? sdst[lane - 1] : -1;
        uint64_t m = __ballot(d0 != dp);
        if (lane == 0) smask = m;
    }
    __syncthreads();

    // run-max over sorted dst, one coalesced atomic per (run, col)
    uint64_t mask = smask;
    int col = tid;
    const uint16_t* zc = &Zl[col * ZSTRIDE];
    float run = 0.f;
#pragma unroll 4
    for (int gi = 0; gi < 16; gi++) {
        int rbase = gi * 4;
        if (rbase >= evalid) break;
        uint2 z4 = *(const uint2*)&zc[rbase];
        float vv[4] = {b2f(z4.x & 0xffffu), b2f_hi(z4.x),
                       b2f(z4.y & 0xffffu), b2f_hi(z4.y)};
#pragma unroll
        for (int i = 0; i < 4; i++) {
            int r = rbase + i;
            if (r >= evalid) break;
            if (r == 0) {
                run = vv[0];
            } else if ((mask >> r) & 1ull) {
                int dp = sdst[r - 1];
                atomicMax(agg + (size_t)dp * 256 + col, encf(run));
                run = vv[i];
            } else {
                run = fmaxf(run, vv[i]);
            }
        }
    }
    if (evalid > 0)
        atomicMax(agg + (size_t)sdst[evalid - 1] * 256 + col, encf(run));
}

// ---------------------------------------------------------------------------
extern "C" void kernel_launch(void* const* d_in, const int* in_sizes, int n_in,
                              void* d_out, int out_size, void* d_ws, size_t ws_size,
                              hipStream_t stream) {
    const void* x_raw   = d_in[0];
    const void* pos_raw = d_in[1];
    const int*  ei_raw  = (const int*)d_in[2];

    int N = in_sizes[0] / 256;     // 50000
    int E = in_sizes[2] / 2;       // 800000

    // ---- workspace layout (256B-aligned chunks) ----
    char* ws = (char*)d_ws;
    size_t off = 0;
    auto alloc = [&](size_t bytes) { void* p = ws + off; off += (bytes + 255) & ~(size_t)255; return p; };

    uint32_t* flags = (uint32_t*)alloc(256);
    uint16_t* WT    = (uint16_t*)alloc(6 * 65536 * sizeof(uint16_t));          // 768 KB
    const uint32_t POS_OFF = 0;
    const uint32_t W1A_OFF = POS_OFF + (uint32_t)(N * 3);
    const uint32_t W2A_OFF = W1A_OFF + 66304;
    const uint32_t W1B_OFF = W2A_OFF + 66304;
    const uint32_t W2B_OFF = W1B_OFF + 65536;
    const uint32_t WD1_OFF = W2B_OFF + 65536;
    const uint32_t WD2_OFF = WD1_OFF + 65536;
    const uint32_t B1A_OFF = WD2_OFF + 65536;
    const uint32_t B1B_OFF = B1A_OFF + 256;
    const uint32_t B2A_OFF = B1B_OFF + 256;
    const uint32_t B2B_OFF = B2A_OFF + 256;
    const uint32_t BD1_OFF = B2B_OFF + 256;
    const uint32_t BD2_OFF = BD1_OFF + 256;
    const uint32_t ARENA_ELEMS = BD2_OFF + 256;
    uint16_t* arena = (uint16_t*)alloc((size_t)ARENA_ELEMS * 2);
    int*      hist  = (int*)alloc((size_t)N * 4);
    int*      curs  = (int*)alloc((size_t)N * 4);
    int*      part  = (int*)alloc(1024 * 4);
    int*      carry = (int*)alloc(1024 * 4);
    int*      esrc  = (int*)alloc((size_t)E * 4);
    int*      edst  = (int*)alloc((size_t)E * 4);
    uint16_t* Qb    = (uint16_t*)alloc((size_t)N * 256 * 2);                   // 25.6 MB
    uint16_t* Gs    = (uint16_t*)alloc((size_t)N * 256 * 2);                   // 25.6 MB (bf16)
    uint32_t* agg   = (uint32_t*)alloc((size_t)N * 256 * 4);                   // 51.2 MB
    uint16_t* d1    = Gs;               // alias: Gs dead after layer-2 edge pass

    uint16_t* posb = arena + POS_OFF;
    uint16_t* w1a = arena + W1A_OFF, * w2a = arena + W2A_OFF;
    uint16_t* w1b = arena + W1B_OFF, * w2b = arena + W2B_OFF;
    uint16_t* wd1 = arena + WD1_OFF, * wd2 = arena + WD2_OFF;
    uint16_t* b1a = arena + B1A_OFF, * b1b = arena + B1B_OFF;
    uint16_t* b2a = arena + B2A_OFF, * b2b = arena + B2B_OFF;
    uint16_t* bd1 = arena + BD1_OFF, * bd2 = arena + BD2_OFF;

    int n4      = N * 64;
    int nbElem  = (n4 + 255) / 256;
    int nbNode  = (N + 63) / 64;
    int nbEdge  = (E + 63) / 64;
    int nbE256  = (E + 255) / 256;
    int nbPos   = (N + 7) / 8;
    int nbScan  = (N + 1023) / 1024;

    // ---- detection + canonicalization (weights/biases/pos only) ----
    detect_fmt<<<1, 64, 0, stream>>>((const uint32_t*)x_raw, (const uint32_t*)ei_raw, flags);

    ConvArgs ca;
    ca.src[0] = pos_raw;  ca.dstOff[0] = POS_OFF; ca.n[0] = (uint32_t)(N * 3);
    ca.src[1] = d_in[3];  ca.dstOff[1] = W1A_OFF; ca.n[1] = 66304;
    ca.src[2] = d_in[7];  ca.dstOff[2] = W2A_OFF; ca.n[2] = 66304;
    ca.src[3] = d_in[5];  ca.dstOff[3] = W1B_OFF; ca.n[3] = 65536;
    ca.src[4] = d_in[9];  ca.dstOff[4] = W2B_OFF; ca.n[4] = 65536;
    ca.src[5] = d_in[11]; ca.dstOff[5] = WD1_OFF; ca.n[5] = 65536;
    ca.src[6] = d_in[13]; ca.dstOff[6] = WD2_OFF; ca.n[6] = 65536;
    ca.src[7] = d_in[4];  ca.dstOff[7] = B1A_OFF; ca.n[7] = 256;
    ca.src[8] = d_in[6];  ca.dstOff[8] = B1B_OFF; ca.n[8] = 256;
    ca.src[9] = d_in[8];  ca.dstOff[9] = B2A_OFF; ca.n[9] = 256;
    ca.src[10] = d_in[10]; ca.dstOff[10] = B2B_OFF; ca.n[10] = 256;
    ca.src[11] = d_in[12]; ca.dstOff[11] = BD1_OFF; ca.n[11] = 256;
    ca.src[12] = d_in[14]; ca.dstOff[12] = BD2_OFF; ca.n[12] = 256;
    {
        uint32_t maxn = (uint32_t)(N * 3);
        dim3 g((maxn + 255) / 256, 13);
        convert_small<<<g, 256, 0, stream>>>(ca, arena, flags);
    }

    // ---- counting sort of edges by dst (once, reused by both layers) ----
    init_hist_agg<<<nbElem, 256, 0, stream>>>(agg, n4, hist, N);
    hist_dst<<<nbE256, 256, 0, stream>>>(ei_raw, E, hist, flags);
    scan_partial<<<nbScan, 1024, 0, stream>>>(hist, curs, part, N);
    scan_carry<<<1, 1024, 0, stream>>>(part, carry, nbScan);
    scan_add<<<nbScan, 1024, 0, stream>>>(curs, carry, N);
    scatter_edges<<<nbE256, 256, 0, stream>>>(ei_raw, E, curs, esrc, edst, flags);

    transpose_w<<<dim3(256, 6), 256, 0, stream>>>(w1a, w1b, w2a, w2b, wd1, wd2, WT);

    // ---- layer 1 ----
    pos_proj<<<nbPos, 256, 0, stream>>>(posb, w1a + 65536, Qb, N);
    gemm_node<2, 0, 0><<<nbNode, 256, 0, stream>>>(
        x_raw, WT + 0 * 65536, b1a, Qb, Gs, N, flags, nullptr);
    edge_gemm_agg<<<nbEdge, 256, 0, stream>>>(Gs, Qb, WT + 1 * 65536, b1b, esrc, edst, E, agg);

    // ---- layer 2 (A = encoded agg, decoded in staging; re-inits agg) ----
    pos_proj<<<nbPos, 256, 0, stream>>>(posb, w2a + 65536, Qb, N);
    gemm_node<1, 0, 1><<<nbNode, 256, 0, stream>>>(
        agg, WT + 2 * 65536, b2a, Qb, Gs, N, flags, agg);
    edge_gemm_agg<<<nbEdge, 256, 0, stream>>>(Gs, Qb, WT + 3 * 65536, b2b, esrc, edst, E, agg);

    // ---- decoder (stage 1 reads encoded agg directly) ----
    gemm_node<1, 1, 0><<<nbNode, 256, 0, stream>>>(
        agg, WT + 4 * 65536, bd1, nullptr, d1, N, flags, nullptr);
    gemm_node<0, 2, 0><<<nbNode, 256, 0, stream>>>(
        d1, WT + 5 * 65536, bd2, nullptr, d_out, N, flags, nullptr);
}

// Round 8
// 684.971 us; speedup vs baseline: 1.2014x; 1.0373x over previous
//
#include <hip/hip_runtime.h>
#include <stdint.h>

// ---------------------------------------------------------------------------
// PointNet-style graph autoencoder, MI355X (gfx950).
//
// R14 = R13 (best: 710us; edge 186us @ VGPR64/4blk) +
//   * decoder_fused: both decoder GEMMs in one kernel. GEMM1 (A=agg decode,
//     W=wd1, relu) writes its 64x256 output tile into LDS in the chunked
//     A-layout [8][64][AB_STRIDE] (40KB -> still 4 blk/CU); GEMM2 reads af
//     straight from that tile (no staging, no barriers) x wd2 -> out.
//     Kills the d1 51.2MB HBM round-trip + one dispatch + one staging
//     pipeline. t-write is a 64x ds_write_b16 scatter (C->A transpose),
//     ~370cyc/wave, far below the saved traffic.
//   * edge pack: relu via one v_pk_max_i16 on the packed bf16 pair instead
//     of two v_max_f32 (max_i16(bf16(x),0) == bf16(relu(x)) for finite x).
// Everything else byte-identical to R13.
// ---------------------------------------------------------------------------

using bf16x8 = __attribute__((ext_vector_type(8))) short;
using f32x4  = __attribute__((ext_vector_type(4))) float;

#define AB_STRIDE 40      // shorts per staged A row (32 k + 8 pad) -> 16B aligned
#define ABUF      2560    // shorts per A buffer / t-chunk slab (64 * AB_STRIDE)
#define ZSTRIDE   68      // shorts per Z column (64 rows + 4 pad)

#define BARRIER_NOVM() asm volatile("s_waitcnt lgkmcnt(0)\n\ts_barrier" ::: "memory")

__device__ __forceinline__ float b2f(uint32_t v16) {          // bf16 bits -> f32
    return __uint_as_float(v16 << 16);
}
__device__ __forceinline__ float b2f_hi(uint32_t w) {         // high bf16 of word
    return __uint_as_float(w & 0xffff0000u);
}
__device__ __forceinline__ uint16_t f2b(float f) {            // f32 -> bf16 (RNE)
    uint32_t u = __float_as_uint(f);
    u += 0x7fffu + ((u >> 16) & 1u);
    return (uint16_t)(u >> 16);
}
#if __has_builtin(__builtin_amdgcn_cvt_pk_bf16_f32)
__device__ __forceinline__ uint32_t pack2bf(float lo, float hi) {
    auto r = __builtin_amdgcn_cvt_pk_bf16_f32(lo, hi);   // RNE
    uint32_t u; __builtin_memcpy(&u, &r, 4); return u;
}
#else
__device__ __forceinline__ uint32_t pack2bf(float lo, float hi) {
    return (uint32_t)f2b(lo) | ((uint32_t)f2b(hi) << 16);
}
#endif
// packed bf16 relu: max_i16(x,0) == bf16(relu) for finite bf16 (sign-mag order)
__device__ __forceinline__ uint32_t pk_relu_bf2(uint32_t w) {
    uint32_t r;
    asm("v_pk_max_i16 %0, %1, 0" : "=v"(r) : "v"(w));
    return r;
}
// monotone float<->uint mapping for atomicMax-based segment_max
__device__ __forceinline__ uint32_t encf(float f) {
    uint32_t u = __float_as_uint(f);
    return (u & 0x80000000u) ? ~u : (u | 0x80000000u);
}
__device__ __forceinline__ float decf(uint32_t k) {
    uint32_t u = (k & 0x80000000u) ? (k & 0x7fffffffu) : ~k;
    return __uint_as_float(u);
}

// ---------------------------------------------------------------------------
// Dtype detection. flags[0]=1 if float tensors are fp32 (else bf16),
// flags[1]=1 if edge_index is int64 (else int32).
// ---------------------------------------------------------------------------
__global__ void detect_fmt(const uint32_t* __restrict__ x,
                           const uint32_t* __restrict__ ei,
                           uint32_t* __restrict__ flags) {
    if (threadIdx.x == 0 && blockIdx.x == 0) {
        int plaus = 0;
        for (int i = 0; i < 64; i++) {
            uint32_t v = x[i];
            uint32_t e = (v >> 23) & 0xffu;
            if (v == 0u || (e >= 96u && e <= 150u)) plaus++;
        }
        flags[0] = (plaus >= 48) ? 1u : 0u;
        int zeros = 0;
        for (int i = 0; i < 16; i++)
            if (ei[2 * i + 1] == 0u) zeros++;
        flags[1] = (zeros == 16) ? 1u : 0u;
    }
}

struct ConvArgs {
    const void* src[13];
    uint32_t dstOff[13];
    uint32_t n[13];
};

// batched small float tensors -> canonical bf16 arena
__global__ __launch_bounds__(256) void convert_small(
        ConvArgs a, uint16_t* __restrict__ dstBase, const uint32_t* __restrict__ flags) {
    bool isf32 = flags[0] != 0u;
    int t = blockIdx.y;
    int i = blockIdx.x * 256 + threadIdx.x;
    if (i >= (int)a.n[t]) return;
    uint16_t* d = dstBase + a.dstOff[t];
    d[i] = isf32 ? f2b(((const float*)a.src[t])[i]) : ((const uint16_t*)a.src[t])[i];
}

// ---------------------------------------------------------------------------
// Counting sort of edges by dst (parallel 3-kernel scan).
// ---------------------------------------------------------------------------
// fused: agg := enc(+0) everywhere; hist := 0 (both uint4-wide)
__global__ __launch_bounds__(256) void init_hist_agg(
        uint32_t* __restrict__ agg, int n4, int* __restrict__ hist, int N) {
    int i = blockIdx.x * 256 + threadIdx.x;
    if (i < n4) {
        uint4 v = {0x80000000u, 0x80000000u, 0x80000000u, 0x80000000u};
        ((uint4*)agg)[i] = v;
    }
    int i4 = i * 4;
    if (i4 + 3 < N) {
        uint4 z = {0, 0, 0, 0};
        ((uint4*)hist)[i] = z;
    } else if (i4 < N) {
        for (int j = i4; j < N; j++) hist[j] = 0;
    }
}

__global__ __launch_bounds__(256) void hist_dst(
        const int* __restrict__ ei_raw, int E, int* __restrict__ hist,
        const uint32_t* __restrict__ flags) {
    bool i64 = flags[1] != 0u;
    int e = blockIdx.x * 256 + threadIdx.x;
    if (e < E) {
        int d = i64 ? ei_raw[2 * (E + e)] : ei_raw[E + e];
        atomicAdd(&hist[d], 1);
    }
}

// per-1024-chunk exclusive scan + chunk totals
__global__ __launch_bounds__(1024) void scan_partial(
        const int* __restrict__ hist, int* __restrict__ cursor,
        int* __restrict__ part, int N) {
    __shared__ int wsum[16];
    int tid = threadIdx.x, lane = tid & 63, wid = tid >> 6;
    int base = blockIdx.x * 1024;
    int v = (base + tid < N) ? hist[base + tid] : 0;
    int x = v;
#pragma unroll
    for (int s = 1; s < 64; s <<= 1) {
        int t = __shfl_up(x, s, 64);
        if (lane >= s) x += t;
    }
    if (lane == 63) wsum[wid] = x;
    __syncthreads();
    if (wid == 0 && lane < 16) {
        int w = wsum[lane];
#pragma unroll
        for (int s = 1; s < 16; s <<= 1) {
            int t = __shfl_up(w, s, 64);
            if (lane >= s) w += t;
        }
        wsum[lane] = w;
    }
    __syncthreads();
    int wbase = (wid > 0) ? wsum[wid - 1] : 0;
    if (base + tid < N) cursor[base + tid] = x - v + wbase;
    if (tid == 0) part[blockIdx.x] = wsum[15];
}

// exclusive scan of chunk totals (B <= 1024)
__global__ __launch_bounds__(1024) void scan_carry(
        const int* __restrict__ part, int* __restrict__ carry, int B) {
    __shared__ int wsum[16];
    int tid = threadIdx.x, lane = tid & 63, wid = tid >> 6;
    int v = (tid < B) ? part[tid] : 0;
    int x = v;
#pragma unroll
    for (int s = 1; s < 64; s <<= 1) {
        int t = __shfl_up(x, s, 64);
        if (lane >= s) x += t;
    }
    if (lane == 63) wsum[wid] = x;
    __syncthreads();
    if (wid == 0 && lane < 16) {
        int w = wsum[lane];
#pragma unroll
        for (int s = 1; s < 16; s <<= 1) {
            int t = __shfl_up(w, s, 64);
            if (lane >= s) w += t;
        }
        wsum[lane] = w;
    }
    __syncthreads();
    int wbase = (wid > 0) ? wsum[wid - 1] : 0;
    if (tid < B) carry[tid] = x - v + wbase;
}

__global__ __launch_bounds__(1024) void scan_add(
        int* __restrict__ cursor, const int* __restrict__ carry, int N) {
    int i = blockIdx.x * 1024 + threadIdx.x;
    if (i < N) cursor[i] += carry[blockIdx.x];
}

__global__ __launch_bounds__(256) void scatter_edges(
        const int* __restrict__ ei_raw, int E, int* __restrict__ cursor,
        int* __restrict__ esrc, int* __restrict__ edst,
        const uint32_t* __restrict__ flags) {
    bool i64 = flags[1] != 0u;
    int e = blockIdx.x * 256 + threadIdx.x;
    if (e < E) {
        int s = i64 ? ei_raw[2 * e] : ei_raw[e];
        int d = i64 ? ei_raw[2 * (E + e)] : ei_raw[E + e];
        int p = atomicAdd(&cursor[d], 1);
        esrc[p] = s;
        edst[p] = d;
    }
}

// ---------------------------------------------------------------------------
// Transpose+chunk-tile the 6 [256x256] B-matrices into WT (32-k chunks):
//   WT[w][ (k>>5)*8192 + n*32 + (k&31) ] = W[k*256 + n]
// ---------------------------------------------------------------------------
__global__ __launch_bounds__(256) void transpose_w(
        const uint16_t* s0, const uint16_t* s1, const uint16_t* s2,
        const uint16_t* s3, const uint16_t* s4, const uint16_t* s5,
        uint16_t* dst) {
    const uint16_t* srcs[6] = {s0, s1, s2, s3, s4, s5};
    const uint16_t* src = srcs[blockIdx.y];
    uint16_t* d = dst + (size_t)blockIdx.y * 65536;
    int k = blockIdx.x;          // grid.x = 256
    int n = threadIdx.x;
    d[(k >> 5) * 8192 + n * 32 + (k & 31)] = src[k * 256 + n];
}

// Q[i][c] = sum_d pos[i][d] * wpos[d][c]   (wpos = wA rows 256..258)
// vectorized: 8 rows/block, 32 threads/row, uint4 (16B) stores.
__global__ __launch_bounds__(256) void pos_proj(
        const uint16_t* pos, const uint16_t* wpos, uint16_t* Q, int N) {
    int t = threadIdx.x;
    int r = t >> 5, c8 = (t & 31) * 8;
    int i = blockIdx.x * 8 + r;
    if (i >= N) return;
    uint4 wv0 = *(const uint4*)(wpos + c8);
    uint4 wv1 = *(const uint4*)(wpos + 256 + c8);
    uint4 wv2 = *(const uint4*)(wpos + 512 + c8);
    float p0 = b2f(pos[i * 3 + 0]);
    float p1 = b2f(pos[i * 3 + 1]);
    float p2 = b2f(pos[i * 3 + 2]);
    uint32_t w0[4] = {wv0.x, wv0.y, wv0.z, wv0.w};
    uint32_t w1[4] = {wv1.x, wv1.y, wv1.z, wv1.w};
    uint32_t w2[4] = {wv2.x, wv2.y, wv2.z, wv2.w};
    uint32_t o[4];
#pragma unroll
    for (int j = 0; j < 4; j++) {
        float lo = p0 * b2f(w0[j] & 0xffffu) + p1 * b2f(w1[j] & 0xffffu) + p2 * b2f(w2[j] & 0xffffu);
        float hi = p0 * b2f_hi(w0[j]) + p1 * b2f_hi(w1[j]) + p2 * b2f_hi(w2[j]);
        o[j] = pack2bf(lo, hi);
    }
    uint4 ov = {o[0], o[1], o[2], o[3]};
    *(uint4*)(Q + (size_t)i * 256 + c8) = ov;
}

// ---------------------------------------------------------------------------
// Node GEMM, R11 edge pipeline ((256,3); A dbuf in LDS, reg prefetch across
// one lgkm-only barrier; B fragments from L2-hot WT pre-barrier, live
// across). A-staging converts per AMODE:
//   AMODE 1: A is agg-encoded u32 rows -> decf -> bf16; REINIT=1 writes
//            enc(0) back after the K-loop (rows owned by this block).
//   AMODE 2: A is raw x: f32 (convert) or bf16 (pass-through) per flags[0]
// OUTMODE 0: bf16 +bias +Q.
// ---------------------------------------------------------------------------
template <int AMODE, int OUTMODE, int REINIT>
__global__ __launch_bounds__(256, 3) void gemm_node(
        const void* __restrict__ Araw, const uint16_t* __restrict__ BT,
        const uint16_t* __restrict__ bias, const uint16_t* __restrict__ Qadd,
        void* __restrict__ out, int M, const uint32_t* __restrict__ flags,
        uint32_t* __restrict__ aggwb) {
    __shared__ __align__(16) uint16_t Al[2 * 64 * AB_STRIDE];   // 10240 B
    int tid = threadIdx.x;
    int tileM = blockIdx.x;
    int wave = tid >> 6, lane = tid & 63, lrow = lane & 15, quad = lane >> 4;
    int row = tid >> 2, kq = (tid & 3) * 8;
    f32x4 acc[4][4] = {};

    int rg = tileM * 64 + row;
    bool rok = rg < M;
    int rgc = rok ? rg : (M - 1);            // clamp: keep vm counts uniform
    bool isf32 = false;
    if (AMODE == 2) isf32 = flags[0] != 0u;

    const uint16_t* a16 = (const uint16_t*)Araw + (size_t)rgc * 256 + kq;
    const uint32_t* a32 = (const uint32_t*)Araw + (size_t)rgc * 256 + kq;
    const uint16_t* bfrag = BT + (wave * 64 + lrow) * 32 + quad * 8;
    uint16_t* awr = Al + row * AB_STRIDE + kq;
    const uint16_t* ard = Al + lrow * AB_STRIDE + quad * 8;

    // prefetch A chunk 0 (p0 [, p1] live across the barrier)
    uint4 p0 = {0, 0, 0, 0}, p1 = {0, 0, 0, 0};
    if (AMODE == 1) {
        p0 = *(const uint4*)a32; p1 = *(const uint4*)(a32 + 4);
    } else {
        if (isf32) { p0 = *(const uint4*)a32; p1 = *(const uint4*)(a32 + 4); }
        else       { p0 = *(const uint4*)a16; }
    }

#pragma unroll
    for (int kc = 0; kc < 256; kc += 32) {
        int buf = (kc >> 5) & 1;
        // stage A chunk -> Al[buf], converting per AMODE
        uint4 wv;
        if (AMODE == 2 && !isf32) {
            wv = p0;
        } else if (AMODE == 1) {
            uint32_t a[8] = {p0.x, p0.y, p0.z, p0.w, p1.x, p1.y, p1.z, p1.w};
            wv.x = pack2bf(decf(a[0]), decf(a[1]));
            wv.y = pack2bf(decf(a[2]), decf(a[3]));
            wv.z = pack2bf(decf(a[4]), decf(a[5]));
            wv.w = pack2bf(decf(a[6]), decf(a[7]));
        } else {   // raw f32
            wv.x = pack2bf(__uint_as_float(p0.x), __uint_as_float(p0.y));
            wv.y = pack2bf(__uint_as_float(p0.z), __uint_as_float(p0.w));
            wv.z = pack2bf(__uint_as_float(p1.x), __uint_as_float(p1.y));
            wv.w = pack2bf(__uint_as_float(p1.z), __uint_as_float(p1.w));
        }
        *(uint4*)(awr + buf * ABUF) = wv;
        // B fragments for this chunk, straight from L2 (live across barrier)
        const uint16_t* bp = bfrag + (kc >> 5) * 8192;
        bf16x8 bfv[4];
#pragma unroll
        for (int c = 0; c < 4; c++) bfv[c] = *(const bf16x8*)(bp + c * 512);
        // prefetch next A chunk (stays in flight across the barrier)
        if (kc < 224) {
            if (AMODE == 1) {
                p0 = *(const uint4*)(a32 + kc + 32);
                p1 = *(const uint4*)(a32 + kc + 36);
            } else {
                if (isf32) { p0 = *(const uint4*)(a32 + kc + 32);
                             p1 = *(const uint4*)(a32 + kc + 36); }
                else       { p0 = *(const uint4*)(a16 + kc + 32); }
            }
        }
        BARRIER_NOVM();
        const uint16_t* ar = ard + buf * ABUF;
        bf16x8 af[4];
#pragma unroll
        for (int r = 0; r < 4; r++) af[r] = *(const bf16x8*)(ar + r * 16 * AB_STRIDE);
#pragma unroll
        for (int r = 0; r < 4; r++)
#pragma unroll
            for (int c = 0; c < 4; c++)
                acc[r][c] = __builtin_amdgcn_mfma_f32_16x16x32_bf16(af[r], bfv[c], acc[r][c], 0, 0, 0);
    }

    // agg re-init writeback (layer-2 Gs build): this block owns these rows
    if (AMODE == 1 && REINIT && rok) {
        uint32_t* wb = aggwb + (size_t)rg * 256 + kq;
        uint4 z = {0x80000000u, 0x80000000u, 0x80000000u, 0x80000000u};
#pragma unroll
        for (int kc = 0; kc < 256; kc += 32) {
            *(uint4*)(wb + kc) = z;
            *(uint4*)(wb + kc + 4) = z;
        }
    }

#pragma unroll
    for (int c = 0; c < 4; c++) {
        int col = wave * 64 + c * 16 + lrow;
        float bv = b2f(bias[col]);
#pragma unroll
        for (int r = 0; r < 4; r++) {
#pragma unroll
            for (int i = 0; i < 4; i++) {
                int rw = tileM * 64 + r * 16 + quad * 4 + i;
                if (rw >= M) continue;
                float v = acc[r][c][i] + bv;
                v += b2f(Qadd[(size_t)rw * 256 + col]);
                ((uint16_t*)out)[(size_t)rw * 256 + col] = f2b(v);
            }
        }
    }
}

// ---------------------------------------------------------------------------
// Fused decoder: out = relu(dec(agg) @ wd1 + bd1) @ wd2 + bd2, one kernel.
// GEMM1 = R11 pipeline (A = agg decode); its output tile t (64x256, bf16,
// +bias +relu) is scattered into LDS in the chunked A-layout
// [8][64][AB_STRIDE] (40960 B -> 4 blk/CU). GEMM2 then runs with ZERO
// barriers: af straight from t, bfv from L2-hot WT5, same acc regs reused.
// Kills the d1 51.2MB HBM round-trip + one dispatch.
// ---------------------------------------------------------------------------
__global__ __launch_bounds__(256, 3) void decoder_fused(
        const uint32_t* __restrict__ agg, const uint16_t* __restrict__ BT1,
        const uint16_t* __restrict__ bias1, const uint16_t* __restrict__ BT2,
        const uint16_t* __restrict__ bias2, void* __restrict__ out, int M,
        const uint32_t* __restrict__ flags) {
    __shared__ __align__(16) uint16_t SM[8 * ABUF];   // 40960 B; [0..1]=Al dbuf
    uint16_t* Al = SM;
    int tid = threadIdx.x;
    int tileM = blockIdx.x;
    int wave = tid >> 6, lane = tid & 63, lrow = lane & 15, quad = lane >> 4;
    int row = tid >> 2, kq = (tid & 3) * 8;
    f32x4 acc[4][4] = {};

    int rg = tileM * 64 + row;
    bool rok = rg < M;
    int rgc = rok ? rg : (M - 1);
    bool isf32 = flags[0] != 0u;

    const uint32_t* a32 = agg + (size_t)rgc * 256 + kq;
    const uint16_t* bfrag1 = BT1 + (wave * 64 + lrow) * 32 + quad * 8;
    const uint16_t* bfrag2 = BT2 + (wave * 64 + lrow) * 32 + quad * 8;
    uint16_t* awr = Al + row * AB_STRIDE + kq;
    const uint16_t* ard = Al + lrow * AB_STRIDE + quad * 8;

    uint4 p0 = *(const uint4*)a32;
    uint4 p1 = *(const uint4*)(a32 + 4);

    // ---- GEMM1: t = relu(dec(agg) @ wd1 + bd1) ----
#pragma unroll
    for (int kc = 0; kc < 256; kc += 32) {
        int buf = (kc >> 5) & 1;
        uint32_t a[8] = {p0.x, p0.y, p0.z, p0.w, p1.x, p1.y, p1.z, p1.w};
        uint4 wv;
        wv.x = pack2bf(decf(a[0]), decf(a[1]));
        wv.y = pack2bf(decf(a[2]), decf(a[3]));
        wv.z = pack2bf(decf(a[4]), decf(a[5]));
        wv.w = pack2bf(decf(a[6]), decf(a[7]));
        *(uint4*)(awr + buf * ABUF) = wv;
        const uint16_t* bp = bfrag1 + (kc >> 5) * 8192;
        bf16x8 bfv[4];
#pragma unroll
        for (int c = 0; c < 4; c++) bfv[c] = *(const bf16x8*)(bp + c * 512);
        if (kc < 224) {
            p0 = *(const uint4*)(a32 + kc + 32);
            p1 = *(const uint4*)(a32 + kc + 36);
        }
        BARRIER_NOVM();
        const uint16_t* ar = ard + buf * ABUF;
        bf16x8 af[4];
#pragma unroll
        for (int r = 0; r < 4; r++) af[r] = *(const bf16x8*)(ar + r * 16 * AB_STRIDE);
#pragma unroll
        for (int r = 0; r < 4; r++)
#pragma unroll
            for (int c = 0; c < 4; c++)
                acc[r][c] = __builtin_amdgcn_mfma_f32_16x16x32_bf16(af[r], bfv[c], acc[r][c], 0, 0, 0);
    }

    BARRIER_NOVM();   // all waves done reading Al before t overwrites SM[0..1]

    // ---- scatter t = f2b(relu(acc + bd1)) into chunked A-layout ----
    // col = wave*64 + c*16 + lrow -> chunk = col>>5, k-in-chunk = col&31
#pragma unroll
    for (int c = 0; c < 4; c++) {
        int col = wave * 64 + c * 16 + lrow;
        float bv = b2f(bias1[col]);
        uint16_t* tb = SM + (col >> 5) * ABUF + (col & 31);
#pragma unroll
        for (int r = 0; r < 4; r++) {
#pragma unroll
            for (int i = 0; i < 4; i++) {
                int rr = r * 16 + quad * 4 + i;
                tb[rr * AB_STRIDE] = f2b(fmaxf(acc[r][c][i] + bv, 0.f));
            }
            acc[r][c] = (f32x4){0.f, 0.f, 0.f, 0.f};   // reset for GEMM2
        }
    }
    BARRIER_NOVM();   // t complete and visible

    // ---- GEMM2: out = t @ wd2 + bd2 (no barriers; t is read-only) ----
#pragma unroll
    for (int kc = 0; kc < 256; kc += 32) {
        const uint16_t* tb = SM + (kc >> 5) * ABUF;
        const uint16_t* bp = bfrag2 + (kc >> 5) * 8192;
        bf16x8 af[4], bfv[4];
#pragma unroll
        for (int c = 0; c < 4; c++) bfv[c] = *(const bf16x8*)(bp + c * 512);
#pragma unroll
        for (int r = 0; r < 4; r++)
            af[r] = *(const bf16x8*)(tb + (r * 16 + lrow) * AB_STRIDE + quad * 8);
#pragma unroll
        for (int r = 0; r < 4; r++)
#pragma unroll
            for (int c = 0; c < 4; c++)
                acc[r][c] = __builtin_amdgcn_mfma_f32_16x16x32_bf16(af[r], bfv[c], acc[r][c], 0, 0, 0);
    }

#pragma unroll
    for (int c = 0; c < 4; c++) {
        int col = wave * 64 + c * 16 + lrow;
        float bv = b2f(bias2[col]);
#pragma unroll
        for (int r = 0; r < 4; r++) {
#pragma unroll
            for (int i = 0; i < 4; i++) {
                int rw = tileM * 64 + r * 16 + quad * 4 + i;
                if (rw >= M) continue;
                float v = acc[r][c][i] + bv;
                if (isf32) ((float*)out)[(size_t)rw * 256 + col] = v;
                else       ((uint16_t*)out)[(size_t)rw * 256 + col] = f2b(v);
            }
        }
    }
}

// ---------------------------------------------------------------------------
// Edge kernel over dst-SORTED edges. R11 structure (best measured), with
// relu via one v_pk_max_i16 on the packed pair. Tile = 64 edges x 256 cols.
// Per chunk: pack (sub, cvt_pk, pk_relu) -> Al[buf]; load bfv[4] (live
// across); prefetch gq(k+1) (live across); ONE lgkm-only barrier; ds_read
// af; 16 MFMAs. Epilogue: Z parked col-major in LDS (overlay); run-max scan
// with ballot mask; one coalesced atomicMax per (run, col).
// ---------------------------------------------------------------------------
__global__ __launch_bounds__(256, 3) void edge_gemm_agg(
        const uint16_t* __restrict__ Gs16, const uint16_t* __restrict__ Qb,
        const uint16_t* __restrict__ BT, const uint16_t* __restrict__ bias,
        const int* __restrict__ esrc, const int* __restrict__ edst, int E,
        uint32_t* __restrict__ agg) {
    __shared__ __align__(16) uint16_t SM[256 * ZSTRIDE];     // 34816 B
    uint16_t* Al = SM;                       // dbuf: 2 x 64 x AB_STRIDE = 10240 B
    uint16_t* Zl = SM;                       // overlay: col-major 256 x ZSTRIDE
    __shared__ int sdst[64];
    __shared__ uint64_t smask;
    int tid = threadIdx.x;
    int ebase = blockIdx.x * 64;
    int evalid = (E - ebase < 64) ? (E - ebase) : 64;
    if (tid < 64) sdst[tid] = (tid < evalid) ? edst[ebase + tid] : 0;  // wave 0

    int wave = tid >> 6, lane = tid & 63, lrow = lane & 15, quad = lane >> 4;
    int row = tid >> 2, kq = (tid & 3) * 8;
    int er = (row < evalid) ? row : (evalid - 1);
    int s = esrc[ebase + er];
    int d = edst[ebase + er];
    const uint16_t* gbase = Gs16 + (size_t)s * 256 + kq;
    const uint16_t* qbase = Qb   + (size_t)d * 256 + kq;
    const uint16_t* bfrag = BT + (wave * 64 + lrow) * 32 + quad * 8;
    uint16_t* awr = Al + row * AB_STRIDE + kq;
    const uint16_t* ard = Al + lrow * AB_STRIDE + quad * 8;

    f32x4 acc[4][4] = {};
    uint4 g = *(const uint4*)gbase;          // gathers for chunk 0
    uint4 q = *(const uint4*)qbase;

#pragma unroll
    for (int kc = 0; kc < 256; kc += 32) {
        int buf = (kc >> 5) & 1;
        // pack current chunk: pk_relu(bf16(g - q)) -> Al[buf]
        uint32_t gw[4] = {g.x, g.y, g.z, g.w};
        uint32_t qw[4] = {q.x, q.y, q.z, q.w};
        uint32_t mw[4];
#pragma unroll
        for (int j = 0; j < 4; j++) {
            float lo = b2f(gw[j] & 0xffffu) - b2f(qw[j] & 0xffffu);
            float hi = b2f_hi(gw[j]) - b2f_hi(qw[j]);
            mw[j] = pk_relu_bf2(pack2bf(lo, hi));
        }
        uint4 wv = {mw[0], mw[1], mw[2], mw[3]};
        *(uint4*)(awr + buf * ABUF) = wv;
        // B(k) fragments from L2-hot WT -- issued pre-barrier, live across
        const uint16_t* bp = bfrag + (kc >> 5) * 8192;
        bf16x8 bfv[4];
#pragma unroll
        for (int c = 0; c < 4; c++) bfv[c] = *(const bf16x8*)(bp + c * 512);
        // prefetch gathers(k+1): fly across the barrier, land during MFMAs
        if (kc < 224) {
            g = *(const uint4*)(gbase + kc + 32);
            q = *(const uint4*)(qbase + kc + 32);
        }
        BARRIER_NOVM();
        const uint16_t* ar = ard + buf * ABUF;
        bf16x8 af[4];
#pragma unroll
        for (int r = 0; r < 4; r++) af[r] = *(const bf16x8*)(ar + r * 16 * AB_STRIDE);
#pragma unroll
        for (int r = 0; r < 4; r++)
#pragma unroll
            for (int c = 0; c < 4; c++)
                acc[r][c] = __builtin_amdgcn_mfma_f32_16x16x32_bf16(af[r], bfv[c], acc[r][c], 0, 0, 0);
    }
    __syncthreads();          // all waves done reading Al before Z overlays it

    // park z = acc + bias in LDS col-major as bf16 (RNE monotone: commutes w/ max)
    float bv[4];
#pragma unroll
    for (int c = 0; c < 4; c++) bv[c] = b2f(bias[wave * 64 + c * 16 + lrow]);
#pragma unroll
    for (int c = 0; c < 4; c++) {
        int col = wave * 64 + c * 16 + lrow;
#pragma unroll
        for (int r = 0; r < 4; r++) {
            uint2 z4 = {pack2bf(acc[r][c][0] + bv[c], acc[r][c][1] + bv[c]),
                        pack2bf(acc[r][c][2] + bv[c], acc[r][c][3] + bv[c])};
            *(uint2*)&Zl[col * ZSTRIDE + r * 16 + quad * 4] = z4;
        }
    }
    // run-boundary mask (uniform): bit r set where sdst[r] != sdst[r-1]
    if (wave == 0) {
        int d0 = sdst[lane];
        int dp = (lane > 0) ? sdst[lane - 1] : -1;
        uint64_t m = __ballot(d0 != dp);
        if (lane == 0) smask = m;
    }
    __syncthreads();

    // run-max over sorted dst, one coalesced atomic per (run, col)
    uint64_t mask = smask;
    int col = tid;
    const uint16_t* zc = &Zl[col * ZSTRIDE];
    float run = 0.f;
#pragma unroll 4
    for (int gi = 0; gi < 16; gi++) {
        int rbase = gi * 4;
        if (rbase >= evalid) break;
        uint2 z4 = *(const uint2*)&zc[rbase];
        float vv[4] = {b2f(z4.x & 0xffffu), b2f_hi(z4.x),
                       b2f(z4.y & 0xffffu), b2f_hi(z4.y)};
#pragma unroll
        for (int i = 0; i < 4; i++) {
            int r = rbase + i;
            if (r >= evalid) break;
            if (r == 0) {
                run = vv[0];
            } else if ((mask >> r) & 1ull) {
                int dp = sdst[r - 1];
                atomicMax(agg + (size_t)dp * 256 + col, encf(run));
                run = vv[i];
            } else {
                run = fmaxf(run, vv[i]);
            }
        }
    }
    if (evalid > 0)
        atomicMax(agg + (size_t)sdst[evalid - 1] * 256 + col, encf(run));
}

// ---------------------------------------------------------------------------
extern "C" void kernel_launch(void* const* d_in, const int* in_sizes, int n_in,
                              void* d_out, int out_size, void* d_ws, size_t ws_size,
                              hipStream_t stream) {
    const void* x_raw   = d_in[0];
    const void* pos_raw = d_in[1];
    const int*  ei_raw  = (const int*)d_in[2];

    int N = in_sizes[0] / 256;     // 50000
    int E = in_sizes[2] / 2;       // 800000

    // ---- workspace layout (256B-aligned chunks) ----
    char* ws = (char*)d_ws;
    size_t off = 0;
    auto alloc = [&](size_t bytes) { void* p = ws + off; off += (bytes + 255) & ~(size_t)255; return p; };

    uint32_t* flags = (uint32_t*)alloc(256);
    uint16_t* WT    = (uint16_t*)alloc(6 * 65536 * sizeof(uint16_t));          // 768 KB
    const uint32_t POS_OFF = 0;
    const uint32_t W1A_OFF = POS_OFF + (uint32_t)(N * 3);
    const uint32_t W2A_OFF = W1A_OFF + 66304;
    const uint32_t W1B_OFF = W2A_OFF + 66304;
    const uint32_t W2B_OFF = W1B_OFF + 65536;
    const uint32_t WD1_OFF = W2B_OFF + 65536;
    const uint32_t WD2_OFF = WD1_OFF + 65536;
    const uint32_t B1A_OFF = WD2_OFF + 65536;
    const uint32_t B1B_OFF = B1A_OFF + 256;
    const uint32_t B2A_OFF = B1B_OFF + 256;
    const uint32_t B2B_OFF = B2A_OFF + 256;
    const uint32_t BD1_OFF = B2B_OFF + 256;
    const uint32_t BD2_OFF = BD1_OFF + 256;
    const uint32_t ARENA_ELEMS = BD2_OFF + 256;
    uint16_t* arena = (uint16_t*)alloc((size_t)ARENA_ELEMS * 2);
    int*      hist  = (int*)alloc((size_t)N * 4);
    int*      curs  = (int*)alloc((size_t)N * 4);
    int*      part  = (int*)alloc(1024 * 4);
    int*      carry = (int*)alloc(1024 * 4);
    int*      esrc  = (int*)alloc((size_t)E * 4);
    int*      edst  = (int*)alloc((size_t)E * 4);
    uint16_t* Qb    = (uint16_t*)alloc((size_t)N * 256 * 2);                   // 25.6 MB
    uint16_t* Gs    = (uint16_t*)alloc((size_t)N * 256 * 2);                   // 25.6 MB (bf16)
    uint32_t* agg   = (uint32_t*)alloc((size_t)N * 256 * 4);                   // 51.2 MB

    uint16_t* posb = arena + POS_OFF;
    uint16_t* w1a = arena + W1A_OFF, * w2a = arena + W2A_OFF;
    uint16_t* w1b = arena + W1B_OFF, * w2b = arena + W2B_OFF;
    uint16_t* wd1 = arena + WD1_OFF, * wd2 = arena + WD2_OFF;
    uint16_t* b1a = arena + B1A_OFF, * b1b = arena + B1B_OFF;
    uint16_t* b2a = arena + B2A_OFF, * b2b = arena + B2B_OFF;
    uint16_t* bd1 = arena + BD1_OFF, * bd2 = arena + BD2_OFF;

    int n4      = N * 64;
    int nbElem  = (n4 + 255) / 256;
    int nbNode  = (N + 63) / 64;
    int nbEdge  = (E + 63) / 64;
    int nbE256  = (E + 255) / 256;
    int nbPos   = (N + 7) / 8;
    int nbScan  = (N + 1023) / 1024;

    // ---- detection + canonicalization (weights/biases/pos only) ----
    detect_fmt<<<1, 64, 0, stream>>>((const uint32_t*)x_raw, (const uint32_t*)ei_raw, flags);

    ConvArgs ca;
    ca.src[0] = pos_raw;  ca.dstOff[0] = POS_OFF; ca.n[0] = (uint32_t)(N * 3);
    ca.src[1] = d_in[3];  ca.dstOff[1] = W1A_OFF; ca.n[1] = 66304;
    ca.src[2] = d_in[7];  ca.dstOff[2] = W2A_OFF; ca.n[2] = 66304;
    ca.src[3] = d_in[5];  ca.dstOff[3] = W1B_OFF; ca.n[3] = 65536;
    ca.src[4] = d_in[9];  ca.dstOff[4] = W2B_OFF; ca.n[4] = 65536;
    ca.src[5] = d_in[11]; ca.dstOff[5] = WD1_OFF; ca.n[5] = 65536;
    ca.src[6] = d_in[13]; ca.dstOff[6] = WD2_OFF; ca.n[6] = 65536;
    ca.src[7] = d_in[4];  ca.dstOff[7] = B1A_OFF; ca.n[7] = 256;
    ca.src[8] = d_in[6];  ca.dstOff[8] = B1B_OFF; ca.n[8] = 256;
    ca.src[9] = d_in[8];  ca.dstOff[9] = B2A_OFF; ca.n[9] = 256;
    ca.src[10] = d_in[10]; ca.dstOff[10] = B2B_OFF; ca.n[10] = 256;
    ca.src[11] = d_in[12]; ca.dstOff[11] = BD1_OFF; ca.n[11] = 256;
    ca.src[12] = d_in[14]; ca.dstOff[12] = BD2_OFF; ca.n[12] = 256;
    {
        uint32_t maxn = (uint32_t)(N * 3);
        dim3 g((maxn + 255) / 256, 13);
        convert_small<<<g, 256, 0, stream>>>(ca, arena, flags);
    }

    // ---- counting sort of edges by dst (once, reused by both layers) ----
    init_hist_agg<<<nbElem, 256, 0, stream>>>(agg, n4, hist, N);
    hist_dst<<<nbE256, 256, 0, stream>>>(ei_raw, E, hist, flags);
    scan_partial<<<nbScan, 1024, 0, stream>>>(hist, curs, part, N);
    scan_carry<<<1, 1024, 0, stream>>>(part, carry, nbScan);
    scan_add<<<nbScan, 1024, 0, stream>>>(curs, carry, N);
    scatter_edges<<<nbE256, 256, 0, stream>>>(ei_raw, E, curs, esrc, edst, flags);

    transpose_w<<<dim3(256, 6), 256, 0, stream>>>(w1a, w1b, w2a, w2b, wd1, wd2, WT);

    // ---- layer 1 ----
    pos_proj<<<nbPos, 256, 0, stream>>>(posb, w1a + 65536, Qb, N);
    gemm_node<2, 0, 0><<<nbNode, 256, 0, stream>>>(
        x_raw, WT + 0 * 65536, b1a, Qb, Gs, N, flags, nullptr);
    edge_gemm_agg<<<nbEdge, 256, 0, stream>>>(Gs, Qb, WT + 1 * 65536, b1b, esrc, edst, E, agg);

    // ---- layer 2 (A = encoded agg, decoded in staging; re-inits agg) ----
    pos_proj<<<nbPos, 256, 0, stream>>>(posb, w2a + 65536, Qb, N);
    gemm_node<1, 0, 1><<<nbNode, 256, 0, stream>>>(
        agg, WT + 2 * 65536, b2a, Qb, Gs, N, flags, agg);
    edge_gemm_agg<<<nbEdge, 256, 0, stream>>>(Gs, Qb, WT + 3 * 65536, b2b, esrc, edst, E, agg);

    // ---- fused decoder ----
    decoder_fused<<<nbNode, 256, 0, stream>>>(
        agg, WT + 4 * 65536, bd1, WT + 5 * 65536, bd2, d_out, N, flags);
}